// Round 11
// baseline (1503.491 us; speedup 1.0000x reference)
//
#include <hip/hip_runtime.h>
#include <cstdint>

#define BT 4096
#define HD 2048
#define VD 32000

typedef __attribute__((ext_vector_type(4))) float float4_t;
typedef __attribute__((ext_vector_type(4))) short short4_t;
typedef __attribute__((ext_vector_type(8))) short short8_t;
typedef __attribute__((ext_vector_type(8))) unsigned short ushort8_t;
typedef __attribute__((ext_vector_type(4))) unsigned int uint4_t;
typedef __attribute__((ext_vector_type(4))) int int4v;
typedef __attribute__((ext_vector_type(8))) int int8v;

constexpr int BM = 128, BN = 128, BK = 32;

// f32 -> bf16 round-to-nearest-even (inputs are normal, no NaN handling needed)
__device__ __forceinline__ unsigned short f2bf(float f) {
  unsigned u = __float_as_uint(f);
  u += 0x7FFFu + ((u >> 16) & 1u);
  return (unsigned short)(u >> 16);
}

__device__ __forceinline__ float bf2f(unsigned short h) {
  return __uint_as_float((unsigned)h << 16);
}

__device__ __forceinline__ short8_t pack8(float4_t a, float4_t b) {
  short8_t h;
  h[0] = (short)f2bf(a.x); h[1] = (short)f2bf(a.y);
  h[2] = (short)f2bf(a.z); h[3] = (short)f2bf(a.w);
  h[4] = (short)f2bf(b.x); h[5] = (short)f2bf(b.y);
  h[6] = (short)f2bf(b.z); h[7] = (short)f2bf(b.w);
  return h;
}

// async global->LDS, 16B per lane; LDS dest is wave-uniform base + lane*16.
__device__ __forceinline__ void async_copy16(const void* g, void* l) {
  __builtin_amdgcn_global_load_lds(
      (__attribute__((address_space(1))) void*)(uintptr_t)(g),
      (__attribute__((address_space(3))) void*)(uint32_t)(uintptr_t)(l),
      16, 0, 0);
}

__global__ __launch_bounds__(256) void cast_f32_to_bf16(
    const float4_t* __restrict__ in, short4_t* __restrict__ out, int n4) {
  for (int i = blockIdx.x * 256 + threadIdx.x; i < n4; i += gridDim.x * 256) {
    float4_t v = in[i];
    short4_t o;
    o.x = (short)f2bf(v.x); o.y = (short)f2bf(v.y);
    o.z = (short)f2bf(v.z); o.w = (short)f2bf(v.w);
    out[i] = o;
  }
}

__device__ __forceinline__ unsigned int pk_fp8x4(float a, float b, float c, float d) {
  int p = __builtin_amdgcn_cvt_pk_fp8_f32(a, b, 0, false);
  p = __builtin_amdgcn_cvt_pk_fp8_f32(c, d, p, true);
  return (unsigned int)p;
}

// Fused f32 -> fp8(e4m3) cast for all four inputs, writing a K-INTERLEAVED
// layout: each 64-elem k-block is stored as 4 x 16B pieces, piece p holding
// logical k {p*8..p*8+7} then {32+p*8..32+p*8+7}. Piece p is exactly MFMA
// lane kq=p's operand pair for a K=64 sub-block -> the GEMM reads one
// ds_read_b128 per fragment sub-block (the verified conflict-free pattern).
// Because A and B use the SAME within-lane k-permutation, any MFMA that
// pairs A-byte j with B-byte j (incl. the K=128 scaled form) sums the same
// products as the canonical layout.
// W is prescaled by 2^6 (exact; N(0,0.02^2) would hit e4m3 denormals);
// the GEMM epilogue multiplies acc by 1/64. Thread 0 seeds out[0] = ln2.
__global__ __launch_bounds__(256) void cast_all_fp8i(
    const float* __restrict__ xs, const float* __restrict__ xt,
    const float* __restrict__ ws, const float* __restrict__ wt,
    uint4_t* __restrict__ oxs, uint4_t* __restrict__ oxt,
    uint4_t* __restrict__ ows, uint4_t* __restrict__ owt,
    float* __restrict__ out) {
  const long XP = (long)BT * HD / 16;  // 16B pieces per X tensor
  const long WP = (long)VD * HD / 16;
  const long total = 2 * (XP + WP);
  const long i0 = blockIdx.x * 256L + threadIdx.x;
  if (i0 == 0) out[0] = 0.6931471805599453f;
  for (long i = i0; i < total; i += gridDim.x * 256L) {
    const float* s; uint4_t* d; float scl; long j = i;
    if (j < XP) { s = xs; d = oxs; scl = 1.f; }
    else if ((j -= XP) < XP) { s = xt; d = oxt; scl = 1.f; }
    else if ((j -= XP) < WP) { s = ws; d = ows; scl = 64.f; }
    else { j -= WP; s = wt; d = owt; scl = 64.f; }
    // piece j -> k-block j>>2, sub-piece p=j&3; elem base e = block*64 + p*8
    const float* sp = s + ((j >> 2) * 64 + (j & 3) * 8);
    float4_t v0 = *(const float4_t*)(sp);
    float4_t v1 = *(const float4_t*)(sp + 4);
    float4_t v2 = *(const float4_t*)(sp + 32);
    float4_t v3 = *(const float4_t*)(sp + 36);
    uint4_t o;
    o.x = pk_fp8x4(v0.x * scl, v0.y * scl, v0.z * scl, v0.w * scl);
    o.y = pk_fp8x4(v1.x * scl, v1.y * scl, v1.z * scl, v1.w * scl);
    o.z = pk_fp8x4(v2.x * scl, v2.y * scl, v2.z * scl, v2.w * scl);
    o.w = pk_fp8x4(v3.x * scl, v3.y * scl, v3.z * scl, v3.w * scl);
    d[j] = o;
  }
}

// legacy swizzle for 128x128 fallback kernels
__device__ __forceinline__ int swz(int row) { return (row ^ (row >> 2)) & 3; }

// ---------------------------------------------------------------------------
// Legacy 128x128 tile (used by fallback ws paths) — unchanged, verified.
// ---------------------------------------------------------------------------
template <bool F32SRC>
__device__ __forceinline__ void ktile(const void* A, const void* B,
                                      float4_t (&acc)[4][4],
                                      unsigned short* As, unsigned short* Bs,
                                      int m0, int n0) {
  const int tid = threadIdx.x;
  const int lane = tid & 63;
  const int wave = tid >> 6;
  const int wm = wave >> 1, wn = wave & 1;
  const int r0 = tid >> 2, c0 = tid & 3;
  const int cg = c0 ^ swz(r0);
  const int row16 = lane & 15, kq = lane >> 4;
  const int kqs = kq ^ swz(row16);
  const int aoff = (wm * 64 + row16) * BK + kqs * 8;
  const int boff = (wn * 64 + row16) * BK + kqs * 8;
  const int lds0 = __builtin_amdgcn_readfirstlane(wave * 1024);
  const int lds1 = __builtin_amdgcn_readfirstlane(4096 + wave * 1024);

  const unsigned short* Ab = nullptr; const unsigned short* Bb = nullptr;
  const float* Af = nullptr; const float* Bf = nullptr;
  if constexpr (!F32SRC) {
    Ab = (const unsigned short*)A + (size_t)(m0 + r0) * HD + cg * 8;
    Bb = (const unsigned short*)B + (size_t)(n0 + r0) * HD + cg * 8;
  } else {
    Af = (const float*)A + (size_t)(m0 + r0) * HD + cg * 8;
    Bf = (const float*)B + (size_t)(n0 + r0) * HD + cg * 8;
  }

  for (int kb = 0; kb < HD / BK; ++kb) {
    const int ke = kb * BK;
    if constexpr (!F32SRC) {
      async_copy16(Ab + ke, (char*)As + lds0);
      async_copy16(Ab + (size_t)64 * HD + ke, (char*)As + lds1);
      async_copy16(Bb + ke, (char*)Bs + lds0);
      async_copy16(Bb + (size_t)64 * HD + ke, (char*)Bs + lds1);
    } else {
      short8_t hA0 = pack8(*(const float4_t*)(Af + ke), *(const float4_t*)(Af + ke + 4));
      short8_t hA1 = pack8(*(const float4_t*)(Af + (size_t)64 * HD + ke),
                           *(const float4_t*)(Af + (size_t)64 * HD + ke + 4));
      short8_t hB0 = pack8(*(const float4_t*)(Bf + ke), *(const float4_t*)(Bf + ke + 4));
      short8_t hB1 = pack8(*(const float4_t*)(Bf + (size_t)64 * HD + ke),
                           *(const float4_t*)(Bf + (size_t)64 * HD + ke + 4));
      *(short8_t*)((char*)As + tid * 16) = hA0;
      *(short8_t*)((char*)As + 4096 + tid * 16) = hA1;
      *(short8_t*)((char*)Bs + tid * 16) = hB0;
      *(short8_t*)((char*)Bs + 4096 + tid * 16) = hB1;
    }
    __syncthreads();
    short8_t af[4], bfv[4];
#pragma unroll
    for (int mi = 0; mi < 4; ++mi) af[mi] = *(const short8_t*)(As + aoff + mi * 16 * BK);
#pragma unroll
    for (int ni = 0; ni < 4; ++ni) bfv[ni] = *(const short8_t*)(Bs + boff + ni * 16 * BK);
#pragma unroll
    for (int mi = 0; mi < 4; ++mi)
#pragma unroll
      for (int ni = 0; ni < 4; ++ni)
        acc[mi][ni] = __builtin_amdgcn_mfma_f32_16x16x32_bf16(af[mi], bfv[ni], acc[mi][ni], 0, 0, 0);
    __syncthreads();
  }
}

// Pass 1 legacy (fallback paths): 128x128 tile.
template <bool F32SRC, bool STORE>
__global__ __launch_bounds__(256, 2) void gemm_pass1(
    const void* A0, const void* A1, const void* B0, const void* B1,
    float* __restrict__ rowsum, unsigned short* __restrict__ store) {
  __shared__ __align__(16) unsigned short As[BM * BK];
  __shared__ __align__(16) unsigned short Bs[BN * BK];
  const int m0 = blockIdx.x * BM;
  const int n0 = blockIdx.y * BN;
  const int z = blockIdx.z;
  const void* A = z ? A1 : A0;
  const void* B = z ? B1 : B0;
  float4_t acc[4][4] = {};
  ktile<F32SRC>(A, B, acc, As, Bs, m0, n0);

  const int tid = threadIdx.x;
  const int lane = tid & 63;
  const int wave = tid >> 6;
  const int wm = wave >> 1, wn = wave & 1;
  const int row16 = lane & 15, kq = lane >> 4;

  if constexpr (STORE) {
    unsigned short* st = store + (size_t)z * BT * VD;
#pragma unroll
    for (int mi = 0; mi < 4; ++mi)
#pragma unroll
      for (int r = 0; r < 4; ++r) {
        const size_t grow = (size_t)(m0 + wm * 64 + mi * 16 + kq * 4 + r);
        const size_t gc0 = (size_t)(n0 + wn * 64 + row16);
#pragma unroll
        for (int ni = 0; ni < 4; ++ni)
          st[grow * VD + gc0 + ni * 16] = f2bf(acc[mi][ni][r]);
      }
  }

  float* rs = rowsum + z * BT;
#pragma unroll
  for (int mi = 0; mi < 4; ++mi)
#pragma unroll
    for (int r = 0; r < 4; ++r) {
      float s = __expf(acc[mi][0][r]) + __expf(acc[mi][1][r]) +
                __expf(acc[mi][2][r]) + __expf(acc[mi][3][r]);
      s += __shfl_xor(s, 1);
      s += __shfl_xor(s, 2);
      s += __shfl_xor(s, 4);
      s += __shfl_xor(s, 8);
      if (row16 == 0) atomicAdd(&rs[m0 + wm * 64 + mi * 16 + kq * 4 + r], s);
    }
}

// ---------------------------------------------------------------------------
// 128x128 fp8 GEMM, v11: MX-scaled K=128 MFMA (unit scales) at 2.28x the
// non-scaled fp8 rate (4661 vs 2047 TF ubench); v10's MFMA pipe was 62% of
// 808us ~= the non-scaled floor, so the rate itself was the binding limit.
//  - mfma_scale_f32_16x16x128_f8f6f4, cbsz=blgp=0 (fp8 e4m3), scale bytes
//    0x7F (E8M0 exponent 127 = x1.0). With unit scales + identical A/B
//    within-lane k-permutation, the result equals the canonical fp8 matmul
//    (pairing is by (kq-group, byte); coverage is a bijection onto [0,128)).
//  - A operand = 32B/lane = two verified k-interleaved 16B pieces (K64
//    sub-blocks kt*128 and kt*128+64): two zero-conflict ds_read_b128 each.
//  - Slot = 32 KB {A0,A1,B0,B1 8KB regions}; ring-2 = 64 KB -> 2 blocks/CU
//    (co-residency covers the vmcnt(0) drain, per v10's confirmed m114
//    mechanism). 16 K128 bodies; 8 gloads/body.
//  - launch_bounds(256,2) -> 256-reg cap; acc 64 + frags 64 + addr ~= 160,
//    no spill (v9 gate: WRITE_SIZE must stay ~576 MB).
// ---------------------------------------------------------------------------
constexpr int NKT16 = HD / 128;  // 16 K-tiles of 128

__global__ __launch_bounds__(256, 2) void gemm128_mx_pass1(
    const unsigned char* __restrict__ fXs, const unsigned char* __restrict__ fXt,
    const unsigned char* __restrict__ fWs, const unsigned char* __restrict__ fWt,
    float* __restrict__ rowsum, unsigned short* __restrict__ store) {
  __shared__ __align__(16) unsigned char lds8[2 * 32768];  // 64 KiB

  const int z = blockIdx.y;
  const unsigned char* A = z ? fXt : fXs;
  const unsigned char* B = z ? fWt : fWs;

  // bijective XCD swizzle: 8000 wg/z, 8000 % 8 == 0, 1000 per XCD.
  const int o = blockIdx.x;
  const int s = (o & 7) * 1000 + (o >> 3);
  const int m0 = (s & 31) * 128;   // m fastest: same-XCD neighbors share W-panel
  const int n0 = (s >> 5) * 128;

  const int tid = threadIdx.x;
  const int lane = tid & 63;
  const int wave = tid >> 6;   // 0..3
  const int wm = wave >> 1;    // 0..1
  const int wn = wave & 1;     // 0..1
  const int row16 = lane & 15, kq = lane >> 4;
  const int rh = row16 >> 1;                        // 3-bit swizzle key (R&7)
  const int cA = (((row16 & 1) << 2) | kq) ^ rh;    // swizzled 16B chunk 0..7

  // Staging source map (inverse-swizzled; LDS dest linear), per 8 KB region.
  const int lr = lane >> 3, lc = lane & 7;
  const int cl = lc ^ lr;
  const int k16 = (cl & 3) * 16;
  const int mloc0 = (wave * 2 + 0) * 16 + 2 * lr + (cl >> 2);
  const int mloc1 = (wave * 2 + 1) * 16 + 2 * lr + (cl >> 2);
  const unsigned char* srcA0 = A + (size_t)(m0 + mloc0) * HD + k16;
  const unsigned char* srcA1 = A + (size_t)(m0 + mloc1) * HD + k16;
  const unsigned char* srcB0 = B + (size_t)(n0 + mloc0) * HD + k16;
  const unsigned char* srcB1 = B + (size_t)(n0 + mloc1) * HD + k16;
  const int stA0 = __builtin_amdgcn_readfirstlane((wave * 2 + 0) * 1024);
  const int stA1 = __builtin_amdgcn_readfirstlane((wave * 2 + 1) * 1024);

  // Slot layout: A-blk0 @0, A-blk1 @8192, B-blk0 @16384, B-blk1 @24576.
#define STAGE(ktv, sl)                                                    \
  do {                                                                    \
    char* _sb = (char*)lds8 + (sl) * 32768;                               \
    const size_t _k0 = (size_t)(ktv) * 128;                               \
    async_copy16(srcA0 + _k0, _sb + stA0);                                \
    async_copy16(srcA1 + _k0, _sb + stA1);                                \
    async_copy16(srcA0 + _k0 + 64, _sb + 8192 + stA0);                    \
    async_copy16(srcA1 + _k0 + 64, _sb + 8192 + stA1);                    \
    async_copy16(srcB0 + _k0, _sb + 16384 + stA0);                        \
    async_copy16(srcB1 + _k0, _sb + 16384 + stA1);                        \
    async_copy16(srcB0 + _k0 + 64, _sb + 24576 + stA0);                   \
    async_copy16(srcB1 + _k0 + 64, _sb + 24576 + stA1);                   \
  } while (0)

  // Prologue: stage tile 0, drain, barrier.
  STAGE(0, 0);
  asm volatile("s_waitcnt vmcnt(0)" ::: "memory");
  __builtin_amdgcn_s_barrier();

  float4_t acc[4][4] = {};
  // Byte offsets of the lane's 16B piece within an 8 KB region.
  const int aoff = (wm * 32 + rh) * 128 + cA * 16;
  const int boff = (wn * 32 + rh) * 128 + cA * 16;

#pragma unroll 1
  for (int kt = 0; kt < NKT16; ++kt) {
    __builtin_amdgcn_sched_barrier(0);  // nothing crosses the K-tile boundary
    const int ktS = (kt + 1 > NKT16 - 1) ? NKT16 - 1 : kt + 1;
    STAGE(ktS, (kt + 1) & 1);  // tail: dead rewrite into the other slot, benign

    const unsigned char* Asl = lds8 + (kt & 1) * 32768;
    const unsigned char* Bsl = Asl + 16384;
    int8v a[4], b[4];
#pragma unroll
    for (int mi = 0; mi < 4; ++mi) {
      int4v lo = *(const int4v*)(Asl + aoff + mi * 1024);
      int4v hi = *(const int4v*)(Asl + 8192 + aoff + mi * 1024);
      a[mi] = (int8v){lo.x, lo.y, lo.z, lo.w, hi.x, hi.y, hi.z, hi.w};
    }
#pragma unroll
    for (int ni = 0; ni < 4; ++ni) {
      int4v lo = *(const int4v*)(Bsl + boff + ni * 1024);
      int4v hi = *(const int4v*)(Bsl + 8192 + boff + ni * 1024);
      b[ni] = (int8v){lo.x, lo.y, lo.z, lo.w, hi.x, hi.y, hi.z, hi.w};
    }

    __builtin_amdgcn_s_setprio(1);
#pragma unroll
    for (int mi = 0; mi < 4; ++mi)
#pragma unroll
      for (int ni = 0; ni < 4; ++ni)
        acc[mi][ni] = __builtin_amdgcn_mfma_scale_f32_16x16x128_f8f6f4(
            a[mi], b[ni], acc[mi][ni], 0, 0, 0, 0x7F, 0, 0x7F);
    __builtin_amdgcn_s_setprio(0);

    // drain this body's staging (next tile); the co-resident block covers it.
    asm volatile("s_waitcnt vmcnt(0)" ::: "memory");
    __builtin_amdgcn_s_barrier();
  }
#undef STAGE

  // Epilogue: undo the W 2^6 prescale, store bf16 logits + per-row sum(exp).
  const float SCL = 0.015625f;  // 1/64
  unsigned short* st = store + (size_t)z * BT * VD;
  float* rs = rowsum + z * BT;
#pragma unroll
  for (int mi = 0; mi < 4; ++mi)
#pragma unroll
    for (int r = 0; r < 4; ++r) {
      const size_t grow = (size_t)(m0 + wm * 64 + mi * 16 + kq * 4 + r);
      const size_t gc0 = (size_t)(n0 + wn * 64 + row16);
      float zv[4];
#pragma unroll
      for (int ni = 0; ni < 4; ++ni) {
        zv[ni] = acc[mi][ni][r] * SCL;
        st[grow * VD + gc0 + ni * 16] = f2bf(zv[ni]);
      }
      float ssum = __expf(zv[0]) + __expf(zv[1]) + __expf(zv[2]) + __expf(zv[3]);
      ssum += __shfl_xor(ssum, 1);
      ssum += __shfl_xor(ssum, 2);
      ssum += __shfl_xor(ssum, 4);
      ssum += __shfl_xor(ssum, 8);
      if (row16 == 0) atomicAdd(&rs[grow], ssum);
    }
}

// stats[i] = log(sum_exp) -> LSE; thread 0 seeds out with +ln2. Used by the
// recompute fallback paths only.
__global__ __launch_bounds__(256) void lse_fix(float* __restrict__ stats,
                                               float* __restrict__ out) {
  const int i = blockIdx.x * 256 + threadIdx.x;
  if (i < 2 * BT) stats[i] = __logf(stats[i]);
  if (i == 0) out[0] = 0.6931471805599453f;
}

// Seed-only kernel (MID fallback path; best path seeds in cast_all_fp8i).
__global__ void seed_out(float* __restrict__ out) {
  out[0] = 0.6931471805599453f;
}

// Pass 2 (materialized path): JSD terms from stored bf16 logits; one block per
// row. Takes RAW exp-sums and computes the LSE log inline (per-block, cheap).
__global__ __launch_bounds__(256) void loss_from_blogits(
    const ushort8_t* __restrict__ zs, const ushort8_t* __restrict__ zt,
    const float* __restrict__ rs, float* __restrict__ out) {
  const int row = blockIdx.x;
  const float es = __logf(rs[row]), et = __logf(rs[BT + row]);
  const ushort8_t* ps = zs + (size_t)row * (VD / 8);
  const ushort8_t* pt = zt + (size_t)row * (VD / 8);
  float local = 0.f;
  for (int i = threadIdx.x; i < VD / 8; i += 256) {
    const ushort8_t a = ps[i], b = pt[i];
#pragma unroll
    for (int c = 0; c < 8; ++c) {
      const float ls = bf2f(a[c]) - es, lt = bf2f(b[c]) - et;
      const float p = __expf(ls), q = __expf(lt);
      local += p * ls + q * lt - (p + q) * __logf(p + q);
    }
  }
  local += __shfl_xor(local, 1);
  local += __shfl_xor(local, 2);
  local += __shfl_xor(local, 4);
  local += __shfl_xor(local, 8);
  local += __shfl_xor(local, 16);
  local += __shfl_xor(local, 32);
  __shared__ float red[4];
  const int lane = threadIdx.x & 63, wave = threadIdx.x >> 6;
  if (lane == 0) red[wave] = local;
  __syncthreads();
  if (threadIdx.x == 0)
    atomicAdd(out, (red[0] + red[1] + red[2] + red[3]) * (0.5f / BT));
}

// Pass 2 (recompute fallback): both GEMM tiles then joint JSD terms.
template <bool F32SRC>
__global__ __launch_bounds__(256, 2) void gemm_loss(
    const void* Asg, const void* Bsg, const void* Atg, const void* Btg,
    const float* __restrict__ lse, float* __restrict__ out) {
  __shared__ __align__(16) unsigned short As[BM * BK];
  __shared__ __align__(16) unsigned short Bs[BN * BK];
  __shared__ float red[4];
  const int m0 = blockIdx.x * BM;
  const int n0 = blockIdx.y * BN;
  float4_t acc_s[4][4] = {};
  ktile<F32SRC>(Asg, Bsg, acc_s, As, Bs, m0, n0);
  float4_t acc_t[4][4] = {};
  ktile<F32SRC>(Atg, Btg, acc_t, As, Bs, m0, n0);

  const int tid = threadIdx.x;
  const int lane = tid & 63;
  const int wave = tid >> 6;
  const int wm = wave >> 1;
  const int kq = lane >> 4;

  float local = 0.f;
#pragma unroll
  for (int mi = 0; mi < 4; ++mi)
#pragma unroll
    for (int r = 0; r < 4; ++r) {
      const int grow = m0 + wm * 64 + mi * 16 + kq * 4 + r;
      const float es = lse[grow], et = lse[BT + grow];
#pragma unroll
      for (int ni = 0; ni < 4; ++ni) {
        const float ls = acc_s[mi][ni][r] - es;
        const float lt = acc_t[mi][ni][r] - et;
        const float p = __expf(ls), q = __expf(lt);
        local += p * ls + q * lt - (p + q) * __logf(p + q);
      }
    }
  local += __shfl_xor(local, 1);
  local += __shfl_xor(local, 2);
  local += __shfl_xor(local, 4);
  local += __shfl_xor(local, 8);
  local += __shfl_xor(local, 16);
  local += __shfl_xor(local, 32);
  if (lane == 0) red[wave] = local;
  __syncthreads();
  if (tid == 0) atomicAdd(out, (red[0] + red[1] + red[2] + red[3]) * (0.5f / BT));
}

extern "C" void kernel_launch(void* const* d_in, const int* in_sizes, int n_in,
                              void* d_out, int out_size, void* d_ws, size_t ws_size,
                              hipStream_t stream) {
  const float* Xs = (const float*)d_in[0];
  const float* Xt = (const float*)d_in[1];
  const float* Ws = (const float*)d_in[2];
  const float* Wt = (const float*)d_in[3];
  float* out = (float*)d_out;
  char* ws = (char*)d_ws;

  const size_t STATS_B = (size_t)2 * BT * sizeof(float);          // 32 KB
  const size_t XB8 = (size_t)BT * HD;                             // fp8 X (8 MB)
  const size_t WB8 = (size_t)VD * HD;                             // fp8 W (65.5 MB)
  const size_t XB = (size_t)BT * HD * 2;                          // bf16 X
  const size_t WB = (size_t)VD * HD * 2;                          // bf16 W
  const size_t LOGIT_B = (size_t)2 * BT * VD * 2;                 // bf16 logits (s+t)
  const size_t FP8_NEED = STATS_B + 2 * XB8 + 2 * WB8 + LOGIT_B;  // ~672 MB
  const size_t PRECAST_NEED = STATS_B + 2 * XB + 2 * WB;          // ~296 MB
  const size_t MID_NEED = STATS_B + LOGIT_B;                      // ~524 MB

  float* stats = (float*)ws;
  hipMemsetAsync(stats, 0, STATS_B, stream);

  const dim3 blk(256);
  const dim3 g1(BT / BM, VD / BN, 2);
  const dim3 g2(BT / BM, VD / BN, 1);
  const int XN4 = BT * HD / 4;
  const int WN4 = VD * HD / 4;

  if (ws_size >= FP8_NEED) {
    // fp8 GEMM path: cast to k-interleaved e4m3 (W prescaled x64), run the
    // 128^2 MX-scaled K=128 pipeline, loss from bf16 logits.
    unsigned char* fXs = (unsigned char*)(ws + STATS_B);
    unsigned char* fXt = fXs + XB8;
    unsigned char* fWs = fXt + XB8;
    unsigned char* fWt = fWs + WB8;
    unsigned short* logits = (unsigned short*)(ws + STATS_B + 2 * XB8 + 2 * WB8);
    cast_all_fp8i<<<dim3(2048), blk, 0, stream>>>(
        Xs, Xt, Ws, Wt,
        (uint4_t*)fXs, (uint4_t*)fXt, (uint4_t*)fWs, (uint4_t*)fWt, out);
    gemm128_mx_pass1<<<dim3((BT / 128) * (VD / 128), 2), dim3(256), 0, stream>>>(
        fXs, fXt, fWs, fWt, stats, logits);
    loss_from_blogits<<<dim3(BT), blk, 0, stream>>>(
        (const ushort8_t*)logits,
        (const ushort8_t*)(logits + (size_t)BT * VD), stats, out);
  } else if (ws_size >= MID_NEED) {
    // no precast: stage f32->bf16 on the fly, materialize bf16 logits
    unsigned short* logits = (unsigned short*)(ws + STATS_B);
    gemm_pass1<true, true><<<g1, blk, 0, stream>>>(Xs, Xt, Ws, Wt, stats, logits);
    seed_out<<<dim3(1), dim3(1), 0, stream>>>(out);
    loss_from_blogits<<<dim3(BT), blk, 0, stream>>>(
        (const ushort8_t*)logits,
        (const ushort8_t*)(logits + (size_t)BT * VD), stats, out);
  } else if (ws_size >= PRECAST_NEED) {
    // precast bf16, recompute logits in pass 2
    unsigned short* bXs = (unsigned short*)(ws + STATS_B);
    unsigned short* bXt = bXs + (size_t)BT * HD;
    unsigned short* bWs = bXt + (size_t)BT * HD;
    unsigned short* bWt = bWs + (size_t)VD * HD;
    cast_f32_to_bf16<<<dim3(512), blk, 0, stream>>>((const float4_t*)Xs, (short4_t*)bXs, XN4);
    cast_f32_to_bf16<<<dim3(512), blk, 0, stream>>>((const float4_t*)Xt, (short4_t*)bXt, XN4);
    cast_f32_to_bf16<<<dim3(2048), blk, 0, stream>>>((const float4_t*)Ws, (short4_t*)bWs, WN4);
    cast_f32_to_bf16<<<dim3(2048), blk, 0, stream>>>((const float4_t*)Wt, (short4_t*)bWt, WN4);
    gemm_pass1<false, false><<<g1, blk, 0, stream>>>(bXs, bXt, bWs, bWt, stats, nullptr);
    lse_fix<<<dim3(32), blk, 0, stream>>>(stats, out);
    gemm_loss<false><<<g2, blk, 0, stream>>>(bXs, bWs, bXt, bWt, stats, out);
  } else {
    // minimal-ws fallback: everything on the fly (needs only 32 KB)
    gemm_pass1<true, false><<<g1, blk, 0, stream>>>(Xs, Xt, Ws, Wt, stats, nullptr);
    lse_fix<<<dim3(32), blk, 0, stream>>>(stats, out);
    gemm_loss<true><<<g2, blk, 0, stream>>>(Xs, Ws, Xt, Wt, stats, out);
  }
  (void)in_sizes; (void)n_in; (void)out_size;
}

// Round 12
// 1491.808 us; speedup vs baseline: 1.0078x; 1.0078x over previous
//
#include <hip/hip_runtime.h>
#include <cstdint>

#define BT 4096
#define HD 2048
#define VD 32000

typedef __attribute__((ext_vector_type(4))) float float4_t;
typedef __attribute__((ext_vector_type(4))) short short4_t;
typedef __attribute__((ext_vector_type(8))) short short8_t;
typedef __attribute__((ext_vector_type(8))) unsigned short ushort8_t;
typedef __attribute__((ext_vector_type(2))) long long2_t;
typedef __attribute__((ext_vector_type(4))) unsigned int uint4_t;

constexpr int BM = 128, BN = 128, BK = 32;

// f32 -> bf16 round-to-nearest-even (inputs are normal, no NaN handling needed)
__device__ __forceinline__ unsigned short f2bf(float f) {
  unsigned u = __float_as_uint(f);
  u += 0x7FFFu + ((u >> 16) & 1u);
  return (unsigned short)(u >> 16);
}

__device__ __forceinline__ float bf2f(unsigned short h) {
  return __uint_as_float((unsigned)h << 16);
}

__device__ __forceinline__ short8_t pack8(float4_t a, float4_t b) {
  short8_t h;
  h[0] = (short)f2bf(a.x); h[1] = (short)f2bf(a.y);
  h[2] = (short)f2bf(a.z); h[3] = (short)f2bf(a.w);
  h[4] = (short)f2bf(b.x); h[5] = (short)f2bf(b.y);
  h[6] = (short)f2bf(b.z); h[7] = (short)f2bf(b.w);
  return h;
}

// async global->LDS, 16B per lane; LDS dest is wave-uniform base + lane*16.
__device__ __forceinline__ void async_copy16(const void* g, void* l) {
  __builtin_amdgcn_global_load_lds(
      (__attribute__((address_space(1))) void*)(uintptr_t)(g),
      (__attribute__((address_space(3))) void*)(uint32_t)(uintptr_t)(l),
      16, 0, 0);
}

__global__ __launch_bounds__(256) void cast_f32_to_bf16(
    const float4_t* __restrict__ in, short4_t* __restrict__ out, int n4) {
  for (int i = blockIdx.x * 256 + threadIdx.x; i < n4; i += gridDim.x * 256) {
    float4_t v = in[i];
    short4_t o;
    o.x = (short)f2bf(v.x); o.y = (short)f2bf(v.y);
    o.z = (short)f2bf(v.z); o.w = (short)f2bf(v.w);
    out[i] = o;
  }
}

__device__ __forceinline__ unsigned int pk_fp8x4(float a, float b, float c, float d) {
  int p = __builtin_amdgcn_cvt_pk_fp8_f32(a, b, 0, false);
  p = __builtin_amdgcn_cvt_pk_fp8_f32(c, d, p, true);
  return (unsigned int)p;
}

// Fused f32 -> fp8(e4m3) cast for all four inputs, writing a K-INTERLEAVED
// layout: each 64-elem k-block is stored as 4 x 16B pieces, piece p holding
// logical k {p*8..p*8+7} then {32+p*8..32+p*8+7}. Piece p is exactly MFMA
// lane kq=p's operand pair for the K=64 tile -> the GEMM can read one
// ds_read_b128 per fragment (the verified conflict-free pattern).
// W is prescaled by 2^6 (exact; N(0,0.02^2) would hit e4m3 denormals);
// the GEMM epilogue multiplies acc by 1/64. Thread 0 seeds out[0] = ln2.
// Also zeroes the rowsum stats (replaces the hipMemsetAsync launch).
__global__ __launch_bounds__(256) void cast_all_fp8i(
    const float* __restrict__ xs, const float* __restrict__ xt,
    const float* __restrict__ ws, const float* __restrict__ wt,
    uint4_t* __restrict__ oxs, uint4_t* __restrict__ oxt,
    uint4_t* __restrict__ ows, uint4_t* __restrict__ owt,
    float* __restrict__ stats, float* __restrict__ out) {
  const long XP = (long)BT * HD / 16;  // 16B pieces per X tensor
  const long WP = (long)VD * HD / 16;
  const long total = 2 * (XP + WP);
  const long i0 = blockIdx.x * 256L + threadIdx.x;
  if (i0 == 0) out[0] = 0.6931471805599453f;
  if (i0 < 2 * BT) stats[i0] = 0.f;
  for (long i = i0; i < total; i += gridDim.x * 256L) {
    const float* s; uint4_t* d; float scl; long j = i;
    if (j < XP) { s = xs; d = oxs; scl = 1.f; }
    else if ((j -= XP) < XP) { s = xt; d = oxt; scl = 1.f; }
    else if ((j -= XP) < WP) { s = ws; d = ows; scl = 64.f; }
    else { j -= WP; s = wt; d = owt; scl = 64.f; }
    // piece j -> k-block j>>2, sub-piece p=j&3; elem base e = block*64 + p*8
    const float* sp = s + ((j >> 2) * 64 + (j & 3) * 8);
    float4_t v0 = *(const float4_t*)(sp);
    float4_t v1 = *(const float4_t*)(sp + 4);
    float4_t v2 = *(const float4_t*)(sp + 32);
    float4_t v3 = *(const float4_t*)(sp + 36);
    uint4_t o;
    o.x = pk_fp8x4(v0.x * scl, v0.y * scl, v0.z * scl, v0.w * scl);
    o.y = pk_fp8x4(v1.x * scl, v1.y * scl, v1.z * scl, v1.w * scl);
    o.z = pk_fp8x4(v2.x * scl, v2.y * scl, v2.z * scl, v2.w * scl);
    o.w = pk_fp8x4(v3.x * scl, v3.y * scl, v3.z * scl, v3.w * scl);
    d[j] = o;
  }
}

// legacy swizzle for 128x128 fallback kernels
__device__ __forceinline__ int swz(int row) { return (row ^ (row >> 2)) & 3; }

// ---------------------------------------------------------------------------
// Legacy 128x128 tile (used by fallback ws paths) — unchanged, verified.
// ---------------------------------------------------------------------------
template <bool F32SRC>
__device__ __forceinline__ void ktile(const void* A, const void* B,
                                      float4_t (&acc)[4][4],
                                      unsigned short* As, unsigned short* Bs,
                                      int m0, int n0) {
  const int tid = threadIdx.x;
  const int lane = tid & 63;
  const int wave = tid >> 6;
  const int wm = wave >> 1, wn = wave & 1;
  const int r0 = tid >> 2, c0 = tid & 3;
  const int cg = c0 ^ swz(r0);
  const int row16 = lane & 15, kq = lane >> 4;
  const int kqs = kq ^ swz(row16);
  const int aoff = (wm * 64 + row16) * BK + kqs * 8;
  const int boff = (wn * 64 + row16) * BK + kqs * 8;
  const int lds0 = __builtin_amdgcn_readfirstlane(wave * 1024);
  const int lds1 = __builtin_amdgcn_readfirstlane(4096 + wave * 1024);

  const unsigned short* Ab = nullptr; const unsigned short* Bb = nullptr;
  const float* Af = nullptr; const float* Bf = nullptr;
  if constexpr (!F32SRC) {
    Ab = (const unsigned short*)A + (size_t)(m0 + r0) * HD + cg * 8;
    Bb = (const unsigned short*)B + (size_t)(n0 + r0) * HD + cg * 8;
  } else {
    Af = (const float*)A + (size_t)(m0 + r0) * HD + cg * 8;
    Bf = (const float*)B + (size_t)(n0 + r0) * HD + cg * 8;
  }

  for (int kb = 0; kb < HD / BK; ++kb) {
    const int ke = kb * BK;
    if constexpr (!F32SRC) {
      async_copy16(Ab + ke, (char*)As + lds0);
      async_copy16(Ab + (size_t)64 * HD + ke, (char*)As + lds1);
      async_copy16(Bb + ke, (char*)Bs + lds0);
      async_copy16(Bb + (size_t)64 * HD + ke, (char*)Bs + lds1);
    } else {
      short8_t hA0 = pack8(*(const float4_t*)(Af + ke), *(const float4_t*)(Af + ke + 4));
      short8_t hA1 = pack8(*(const float4_t*)(Af + (size_t)64 * HD + ke),
                           *(const float4_t*)(Af + (size_t)64 * HD + ke + 4));
      short8_t hB0 = pack8(*(const float4_t*)(Bf + ke), *(const float4_t*)(Bf + ke + 4));
      short8_t hB1 = pack8(*(const float4_t*)(Bf + (size_t)64 * HD + ke),
                           *(const float4_t*)(Bf + (size_t)64 * HD + ke + 4));
      *(short8_t*)((char*)As + tid * 16) = hA0;
      *(short8_t*)((char*)As + 4096 + tid * 16) = hA1;
      *(short8_t*)((char*)Bs + tid * 16) = hB0;
      *(short8_t*)((char*)Bs + 4096 + tid * 16) = hB1;
    }
    __syncthreads();
    short8_t af[4], bfv[4];
#pragma unroll
    for (int mi = 0; mi < 4; ++mi) af[mi] = *(const short8_t*)(As + aoff + mi * 16 * BK);
#pragma unroll
    for (int ni = 0; ni < 4; ++ni) bfv[ni] = *(const short8_t*)(Bs + boff + ni * 16 * BK);
#pragma unroll
    for (int mi = 0; mi < 4; ++mi)
#pragma unroll
      for (int ni = 0; ni < 4; ++ni)
        acc[mi][ni] = __builtin_amdgcn_mfma_f32_16x16x32_bf16(af[mi], bfv[ni], acc[mi][ni], 0, 0, 0);
    __syncthreads();
  }
}

// Pass 1 legacy (fallback paths): 128x128 tile.
template <bool F32SRC, bool STORE>
__global__ __launch_bounds__(256, 2) void gemm_pass1(
    const void* A0, const void* A1, const void* B0, const void* B1,
    float* __restrict__ rowsum, unsigned short* __restrict__ store) {
  __shared__ __align__(16) unsigned short As[BM * BK];
  __shared__ __align__(16) unsigned short Bs[BN * BK];
  const int m0 = blockIdx.x * BM;
  const int n0 = blockIdx.y * BN;
  const int z = blockIdx.z;
  const void* A = z ? A1 : A0;
  const void* B = z ? B1 : B0;
  float4_t acc[4][4] = {};
  ktile<F32SRC>(A, B, acc, As, Bs, m0, n0);

  const int tid = threadIdx.x;
  const int lane = tid & 63;
  const int wave = tid >> 6;
  const int wm = wave >> 1, wn = wave & 1;
  const int row16 = lane & 15, kq = lane >> 4;

  if constexpr (STORE) {
    unsigned short* st = store + (size_t)z * BT * VD;
#pragma unroll
    for (int mi = 0; mi < 4; ++mi)
#pragma unroll
      for (int r = 0; r < 4; ++r) {
        const size_t grow = (size_t)(m0 + wm * 64 + mi * 16 + kq * 4 + r);
        const size_t gc0 = (size_t)(n0 + wn * 64 + row16);
#pragma unroll
        for (int ni = 0; ni < 4; ++ni)
          st[grow * VD + gc0 + ni * 16] = f2bf(acc[mi][ni][r]);
      }
  }

  float* rs = rowsum + z * BT;
#pragma unroll
  for (int mi = 0; mi < 4; ++mi)
#pragma unroll
    for (int r = 0; r < 4; ++r) {
      float s = __expf(acc[mi][0][r]) + __expf(acc[mi][1][r]) +
                __expf(acc[mi][2][r]) + __expf(acc[mi][3][r]);
      s += __shfl_xor(s, 1);
      s += __shfl_xor(s, 2);
      s += __shfl_xor(s, 4);
      s += __shfl_xor(s, 8);
      if (row16 == 0) atomicAdd(&rs[m0 + wm * 64 + mi * 16 + kq * 4 + r], s);
    }
}

// ---------------------------------------------------------------------------
// 128x128 fp8 GEMM, v12 = v10 (co-residency confirmed: 3.6 blocks/CU,
// 808us, MfmaUtil 62%) + RING-3 counted vmcnt (T4):
//  - v10's ring-2 forced a vmcnt(0) drain per body (the just-staged loads
//    are the newest -> can't count). Ring-3 (48 KiB, still 3 blocks/CU)
//    staged 2 tiles ahead lets each body wait vmcnt(4): retires only the
//    PREVIOUS body's 4 loads (~1000cy old), never the in-flight ones.
//  - Residency: tile kt+1 staged at body kt-1, retired by body kt's
//    vmcnt(4) -> resident after the barrier for body kt+1. WAR: STAGE(kt+2)
//    overwrites tile kt-1's slot; its reads lgkm-retired before body
//    kt-1's end barrier. Tail stages clamp to tile 31 (dead writes into
//    already-consumed slots, benign; vmcnt counts stay uniform).
//  - v11 lesson (MX): MFMA-rate gains that cost co-residency are net
//    losses; MX's 64 KiB minimum ring is structurally incompatible.
//  - MX-layout note: fp8 k-interleaved layout unchanged (verified 0
//    conflicts, passed rounds 8/10/11).
// ---------------------------------------------------------------------------
constexpr int NKT8 = HD / 64;  // 32 K-tiles of 64

__global__ __launch_bounds__(256, 3) void gemm128_fp8_pass1(
    const unsigned char* __restrict__ fXs, const unsigned char* __restrict__ fXt,
    const unsigned char* __restrict__ fWs, const unsigned char* __restrict__ fWt,
    float* __restrict__ rowsum, unsigned short* __restrict__ store) {
  __shared__ __align__(16) unsigned char lds8[3 * 16384];  // 48 KiB

  const int z = blockIdx.y;
  const unsigned char* A = z ? fXt : fXs;
  const unsigned char* B = z ? fWt : fWs;

  // bijective XCD swizzle: 8000 wg/z, 8000 % 8 == 0, 1000 per XCD.
  const int o = blockIdx.x;
  const int s = (o & 7) * 1000 + (o >> 3);
  const int m0 = (s & 31) * 128;   // m fastest: same-XCD neighbors share W-panel
  const int n0 = (s >> 5) * 128;

  const int tid = threadIdx.x;
  const int lane = tid & 63;
  const int wave = tid >> 6;   // 0..3
  const int wm = wave >> 1;    // 0..1
  const int wn = wave & 1;     // 0..1
  const int row16 = lane & 15, kq = lane >> 4;
  const int rh = row16 >> 1;                        // 3-bit swizzle key (R&7)
  const int cA = (((row16 & 1) << 2) | kq) ^ rh;    // swizzled 16B chunk 0..7

  // Staging source map (inverse-swizzled; LDS dest linear).
  const int lr = lane >> 3, lc = lane & 7;
  const int cl = lc ^ lr;
  const int k16 = (cl & 3) * 16;
  const int mloc0 = (wave * 2 + 0) * 16 + 2 * lr + (cl >> 2);
  const int mloc1 = (wave * 2 + 1) * 16 + 2 * lr + (cl >> 2);
  const unsigned char* srcA0 = A + (size_t)(m0 + mloc0) * HD + k16;
  const unsigned char* srcA1 = A + (size_t)(m0 + mloc1) * HD + k16;
  const unsigned char* srcB0 = B + (size_t)(n0 + mloc0) * HD + k16;
  const unsigned char* srcB1 = B + (size_t)(n0 + mloc1) * HD + k16;
  const int stA0 = __builtin_amdgcn_readfirstlane((wave * 2 + 0) * 1024);
  const int stA1 = __builtin_amdgcn_readfirstlane((wave * 2 + 1) * 1024);

#define STAGE(ktv, sl)                                                   \
  do {                                                                   \
    char* _sb = (char*)lds8 + (sl) * 16384;                              \
    async_copy16(srcA0 + (size_t)(ktv) * 64, _sb + stA0);                \
    async_copy16(srcA1 + (size_t)(ktv) * 64, _sb + stA1);                \
    async_copy16(srcB0 + (size_t)(ktv) * 64, _sb + 8192 + stA0);         \
    async_copy16(srcB1 + (size_t)(ktv) * 64, _sb + 8192 + stA1);         \
  } while (0)

  // Prologue: stage tiles 0,1; vmcnt(4) retires tile 0; barrier.
  STAGE(0, 0);
  STAGE(1, 1);
  asm volatile("s_waitcnt vmcnt(4)" ::: "memory");
  __builtin_amdgcn_s_barrier();

  float4_t acc[4][4] = {};
  // Byte offsets of the lane's 16B fragment (both k-halves).
  const int aoff = (wm * 32 + rh) * 128 + cA * 16;
  const int boff = (wn * 32 + rh) * 128 + cA * 16;

  int sR = 0, sW = 2;  // read slot (tile kt), write slot ((kt+2)%3)
#pragma unroll 1
  for (int kt = 0; kt < NKT8; ++kt) {
    __builtin_amdgcn_sched_barrier(0);  // nothing crosses the K-tile boundary
    const int ktS = (kt + 2 > NKT8 - 1) ? NKT8 - 1 : kt + 2;
    STAGE(ktS, sW);

    const unsigned char* Asl = lds8 + sR * 16384;
    const unsigned char* Bsl = Asl + 8192;
    long2_t a[4], b[4];
#pragma unroll
    for (int mi = 0; mi < 4; ++mi) a[mi] = *(const long2_t*)(Asl + aoff + mi * 1024);
#pragma unroll
    for (int ni = 0; ni < 4; ++ni) b[ni] = *(const long2_t*)(Bsl + boff + ni * 1024);

    __builtin_amdgcn_s_setprio(1);
#pragma unroll
    for (int mi = 0; mi < 4; ++mi)
#pragma unroll
      for (int ni = 0; ni < 4; ++ni)
        acc[mi][ni] = __builtin_amdgcn_mfma_f32_16x16x32_fp8_fp8(a[mi].x, b[ni].x, acc[mi][ni], 0, 0, 0);
#pragma unroll
    for (int mi = 0; mi < 4; ++mi)
#pragma unroll
      for (int ni = 0; ni < 4; ++ni)
        acc[mi][ni] = __builtin_amdgcn_mfma_f32_16x16x32_fp8_fp8(a[mi].y, b[ni].y, acc[mi][ni], 0, 0, 0);
    __builtin_amdgcn_s_setprio(0);

    // counted wait: retires only the PREVIOUS body's 4 loads; this body's
    // 4 stay in flight across the barrier (T4: never drain to 0).
    asm volatile("s_waitcnt vmcnt(4)" ::: "memory");
    __builtin_amdgcn_s_barrier();
    sR = (sR == 2) ? 0 : sR + 1;
    sW = (sW == 2) ? 0 : sW + 1;
  }
#undef STAGE

  // drain remaining async LDS writes before the wave can exit.
  asm volatile("s_waitcnt vmcnt(0)" ::: "memory");

  // Epilogue: undo the W 2^6 prescale, store bf16 logits + per-row sum(exp).
  const float SCL = 0.015625f;  // 1/64
  unsigned short* st = store + (size_t)z * BT * VD;
  float* rs = rowsum + z * BT;
#pragma unroll
  for (int mi = 0; mi < 4; ++mi)
#pragma unroll
    for (int r = 0; r < 4; ++r) {
      const size_t grow = (size_t)(m0 + wm * 64 + mi * 16 + kq * 4 + r);
      const size_t gc0 = (size_t)(n0 + wn * 64 + row16);
      float zv[4];
#pragma unroll
      for (int ni = 0; ni < 4; ++ni) {
        zv[ni] = acc[mi][ni][r] * SCL;
        st[grow * VD + gc0 + ni * 16] = f2bf(zv[ni]);
      }
      float ssum = __expf(zv[0]) + __expf(zv[1]) + __expf(zv[2]) + __expf(zv[3]);
      ssum += __shfl_xor(ssum, 1);
      ssum += __shfl_xor(ssum, 2);
      ssum += __shfl_xor(ssum, 4);
      ssum += __shfl_xor(ssum, 8);
      if (row16 == 0) atomicAdd(&rs[grow], ssum);
    }
}

// stats[i] = log(sum_exp) -> LSE; thread 0 seeds out with +ln2. Used by the
// recompute fallback paths only.
__global__ __launch_bounds__(256) void lse_fix(float* __restrict__ stats,
                                               float* __restrict__ out) {
  const int i = blockIdx.x * 256 + threadIdx.x;
  if (i < 2 * BT) stats[i] = __logf(stats[i]);
  if (i == 0) out[0] = 0.6931471805599453f;
}

// Seed-only kernel (MID fallback path; best path seeds in cast_all_fp8i).
__global__ void seed_out(float* __restrict__ out) {
  out[0] = 0.6931471805599453f;
}

// Pass 2 (materialized path): JSD terms from stored bf16 logits; one block per
// row. Takes RAW exp-sums and computes the LSE log inline (per-block, cheap).
__global__ __launch_bounds__(256) void loss_from_blogits(
    const ushort8_t* __restrict__ zs, const ushort8_t* __restrict__ zt,
    const float* __restrict__ rs, float* __restrict__ out) {
  const int row = blockIdx.x;
  const float es = __logf(rs[row]), et = __logf(rs[BT + row]);
  const ushort8_t* ps = zs + (size_t)row * (VD / 8);
  const ushort8_t* pt = zt + (size_t)row * (VD / 8);
  float local = 0.f;
  for (int i = threadIdx.x; i < VD / 8; i += 256) {
    const ushort8_t a = ps[i], b = pt[i];
#pragma unroll
    for (int c = 0; c < 8; ++c) {
      const float ls = bf2f(a[c]) - es, lt = bf2f(b[c]) - et;
      const float p = __expf(ls), q = __expf(lt);
      local += p * ls + q * lt - (p + q) * __logf(p + q);
    }
  }
  local += __shfl_xor(local, 1);
  local += __shfl_xor(local, 2);
  local += __shfl_xor(local, 4);
  local += __shfl_xor(local, 8);
  local += __shfl_xor(local, 16);
  local += __shfl_xor(local, 32);
  __shared__ float red[4];
  const int lane = threadIdx.x & 63, wave = threadIdx.x >> 6;
  if (lane == 0) red[wave] = local;
  __syncthreads();
  if (threadIdx.x == 0)
    atomicAdd(out, (red[0] + red[1] + red[2] + red[3]) * (0.5f / BT));
}

// Pass 2 (recompute fallback): both GEMM tiles then joint JSD terms.
template <bool F32SRC>
__global__ __launch_bounds__(256, 2) void gemm_loss(
    const void* Asg, const void* Bsg, const void* Atg, const void* Btg,
    const float* __restrict__ lse, float* __restrict__ out) {
  __shared__ __align__(16) unsigned short As[BM * BK];
  __shared__ __align__(16) unsigned short Bs[BN * BK];
  __shared__ float red[4];
  const int m0 = blockIdx.x * BM;
  const int n0 = blockIdx.y * BN;
  float4_t acc_s[4][4] = {};
  ktile<F32SRC>(Asg, Bsg, acc_s, As, Bs, m0, n0);
  float4_t acc_t[4][4] = {};
  ktile<F32SRC>(Atg, Btg, acc_t, As, Bs, m0, n0);

  const int tid = threadIdx.x;
  const int lane = tid & 63;
  const int wave = tid >> 6;
  const int wm = wave >> 1;
  const int kq = lane >> 4;

  float local = 0.f;
#pragma unroll
  for (int mi = 0; mi < 4; ++mi)
#pragma unroll
    for (int r = 0; r < 4; ++r) {
      const int grow = m0 + wm * 64 + mi * 16 + kq * 4 + r;
      const float es = lse[grow], et = lse[BT + grow];
#pragma unroll
      for (int ni = 0; ni < 4; ++ni) {
        const float ls = acc_s[mi][ni][r] - es;
        const float lt = acc_t[mi][ni][r] - et;
        const float p = __expf(ls), q = __expf(lt);
        local += p * ls + q * lt - (p + q) * __logf(p + q);
      }
    }
  local += __shfl_xor(local, 1);
  local += __shfl_xor(local, 2);
  local += __shfl_xor(local, 4);
  local += __shfl_xor(local, 8);
  local += __shfl_xor(local, 16);
  local += __shfl_xor(local, 32);
  if (lane == 0) red[wave] = local;
  __syncthreads();
  if (tid == 0) atomicAdd(out, (red[0] + red[1] + red[2] + red[3]) * (0.5f / BT));
}

extern "C" void kernel_launch(void* const* d_in, const int* in_sizes, int n_in,
                              void* d_out, int out_size, void* d_ws, size_t ws_size,
                              hipStream_t stream) {
  const float* Xs = (const float*)d_in[0];
  const float* Xt = (const float*)d_in[1];
  const float* Ws = (const float*)d_in[2];
  const float* Wt = (const float*)d_in[3];
  float* out = (float*)d_out;
  char* ws = (char*)d_ws;

  const size_t STATS_B = (size_t)2 * BT * sizeof(float);          // 32 KB
  const size_t XB8 = (size_t)BT * HD;                             // fp8 X (8 MB)
  const size_t WB8 = (size_t)VD * HD;                             // fp8 W (65.5 MB)
  const size_t XB = (size_t)BT * HD * 2;                          // bf16 X
  const size_t WB = (size_t)VD * HD * 2;                          // bf16 W
  const size_t LOGIT_B = (size_t)2 * BT * VD * 2;                 // bf16 logits (s+t)
  const size_t FP8_NEED = STATS_B + 2 * XB8 + 2 * WB8 + LOGIT_B;  // ~672 MB
  const size_t PRECAST_NEED = STATS_B + 2 * XB + 2 * WB;          // ~296 MB
  const size_t MID_NEED = STATS_B + LOGIT_B;                      // ~524 MB

  float* stats = (float*)ws;

  const dim3 blk(256);
  const dim3 g1(BT / BM, VD / BN, 2);
  const dim3 g2(BT / BM, VD / BN, 1);
  const int XN4 = BT * HD / 4;
  const int WN4 = VD * HD / 4;

  if (ws_size >= FP8_NEED) {
    // fp8 GEMM path: cast to k-interleaved e4m3 (W prescaled x64; also
    // zeroes stats + seeds out), 128^2 fp8 ring-3 pipeline, loss from
    // bf16 logits.
    unsigned char* fXs = (unsigned char*)(ws + STATS_B);
    unsigned char* fXt = fXs + XB8;
    unsigned char* fWs = fXt + XB8;
    unsigned char* fWt = fWs + WB8;
    unsigned short* logits = (unsigned short*)(ws + STATS_B + 2 * XB8 + 2 * WB8);
    cast_all_fp8i<<<dim3(2048), blk, 0, stream>>>(
        Xs, Xt, Ws, Wt,
        (uint4_t*)fXs, (uint4_t*)fXt, (uint4_t*)fWs, (uint4_t*)fWt, stats, out);
    gemm128_fp8_pass1<<<dim3((BT / 128) * (VD / 128), 2), dim3(256), 0, stream>>>(
        fXs, fXt, fWs, fWt, stats, logits);
    loss_from_blogits<<<dim3(BT), blk, 0, stream>>>(
        (const ushort8_t*)logits,
        (const ushort8_t*)(logits + (size_t)BT * VD), stats, out);
  } else if (ws_size >= MID_NEED) {
    // no precast: stage f32->bf16 on the fly, materialize bf16 logits
    unsigned short* logits = (unsigned short*)(ws + STATS_B);
    hipMemsetAsync(stats, 0, STATS_B, stream);
    gemm_pass1<true, true><<<g1, blk, 0, stream>>>(Xs, Xt, Ws, Wt, stats, logits);
    seed_out<<<dim3(1), dim3(1), 0, stream>>>(out);
    loss_from_blogits<<<dim3(BT), blk, 0, stream>>>(
        (const ushort8_t*)logits,
        (const ushort8_t*)(logits + (size_t)BT * VD), stats, out);
  } else if (ws_size >= PRECAST_NEED) {
    // precast bf16, recompute logits in pass 2
    unsigned short* bXs = (unsigned short*)(ws + STATS_B);
    unsigned short* bXt = bXs + (size_t)BT * HD;
    unsigned short* bWs = bXt + (size_t)BT * HD;
    unsigned short* bWt = bWs + (size_t)VD * HD;
    hipMemsetAsync(stats, 0, STATS_B, stream);
    cast_f32_to_bf16<<<dim3(512), blk, 0, stream>>>((const float4_t*)Xs, (short4_t*)bXs, XN4);
    cast_f32_to_bf16<<<dim3(512), blk, 0, stream>>>((const float4_t*)Xt, (short4_t*)bXt, XN4);
    cast_f32_to_bf16<<<dim3(2048), blk, 0, stream>>>((const float4_t*)Ws, (short4_t*)bWs, WN4);
    cast_f32_to_bf16<<<dim3(2048), blk, 0, stream>>>((const float4_t*)Wt, (short4_t*)bWt, WN4);
    gemm_pass1<false, false><<<g1, blk, 0, stream>>>(bXs, bXt, bWs, bWt, stats, nullptr);
    lse_fix<<<dim3(32), blk, 0, stream>>>(stats, out);
    gemm_loss<false><<<g2, blk, 0, stream>>>(bXs, bWs, bXt, bWt, stats, out);
  } else {
    // minimal-ws fallback: everything on the fly (needs only 32 KB)
    hipMemsetAsync(stats, 0, STATS_B, stream);
    gemm_pass1<true, false><<<g1, blk, 0, stream>>>(Xs, Xt, Ws, Wt, stats, nullptr);
    lse_fix<<<dim3(32), blk, 0, stream>>>(stats, out);
    gemm_loss<true><<<g2, blk, 0, stream>>>(Xs, Ws, Xt, Wt, stats, out);
  }
  (void)in_sizes; (void)n_in; (void)out_size;
}

// Round 13
// 1415.426 us; speedup vs baseline: 1.0622x; 1.0540x over previous
//
#include <hip/hip_runtime.h>
#include <cstdint>

#define BT 4096
#define HD 2048
#define VD 32000

typedef __attribute__((ext_vector_type(4))) float float4_t;
typedef __attribute__((ext_vector_type(4))) short short4_t;
typedef __attribute__((ext_vector_type(8))) short short8_t;
typedef __attribute__((ext_vector_type(8))) unsigned short ushort8_t;
typedef __attribute__((ext_vector_type(2))) long long2_t;
typedef __attribute__((ext_vector_type(4))) unsigned int uint4_t;

constexpr int BM = 128, BN = 128, BK = 32;

// f32 -> bf16 round-to-nearest-even (inputs are normal, no NaN handling needed)
__device__ __forceinline__ unsigned short f2bf(float f) {
  unsigned u = __float_as_uint(f);
  u += 0x7FFFu + ((u >> 16) & 1u);
  return (unsigned short)(u >> 16);
}

__device__ __forceinline__ float bf2f(unsigned short h) {
  return __uint_as_float((unsigned)h << 16);
}

__device__ __forceinline__ short8_t pack8(float4_t a, float4_t b) {
  short8_t h;
  h[0] = (short)f2bf(a.x); h[1] = (short)f2bf(a.y);
  h[2] = (short)f2bf(a.z); h[3] = (short)f2bf(a.w);
  h[4] = (short)f2bf(b.x); h[5] = (short)f2bf(b.y);
  h[6] = (short)f2bf(b.z); h[7] = (short)f2bf(b.w);
  return h;
}

// async global->LDS, 16B per lane; LDS dest is wave-uniform base + lane*16.
__device__ __forceinline__ void async_copy16(const void* g, void* l) {
  __builtin_amdgcn_global_load_lds(
      (__attribute__((address_space(1))) void*)(uintptr_t)(g),
      (__attribute__((address_space(3))) void*)(uint32_t)(uintptr_t)(l),
      16, 0, 0);
}

__global__ __launch_bounds__(256) void cast_f32_to_bf16(
    const float4_t* __restrict__ in, short4_t* __restrict__ out, int n4) {
  for (int i = blockIdx.x * 256 + threadIdx.x; i < n4; i += gridDim.x * 256) {
    float4_t v = in[i];
    short4_t o;
    o.x = (short)f2bf(v.x); o.y = (short)f2bf(v.y);
    o.z = (short)f2bf(v.z); o.w = (short)f2bf(v.w);
    out[i] = o;
  }
}

__device__ __forceinline__ unsigned int pk_fp8x4(float a, float b, float c, float d) {
  int p = __builtin_amdgcn_cvt_pk_fp8_f32(a, b, 0, false);
  p = __builtin_amdgcn_cvt_pk_fp8_f32(c, d, p, true);
  return (unsigned int)p;
}

// Fused f32 -> fp8(e4m3) cast for all four inputs, writing a K-INTERLEAVED
// layout: each 64-elem k-block is stored as 4 x 16B pieces, piece p holding
// logical k {p*8..p*8+7} then {32+p*8..32+p*8+7}. Piece p is exactly MFMA
// lane kq=p's operand pair for the K=64 tile -> the GEMM can read one
// ds_read_b128 per fragment (the verified conflict-free pattern).
// W is prescaled by 2^6 (exact; N(0,0.02^2) would hit e4m3 denormals);
// the GEMM epilogue multiplies acc by 1/64. Thread 0 seeds out[0] = ln2.
// Also zeroes the rowsum stats (replaces the hipMemsetAsync launch).
// f32 inputs are read ONCE -> nontemporal loads (keep L2/L3 for the GEMM).
__global__ __launch_bounds__(256) void cast_all_fp8i(
    const float* __restrict__ xs, const float* __restrict__ xt,
    const float* __restrict__ ws, const float* __restrict__ wt,
    uint4_t* __restrict__ oxs, uint4_t* __restrict__ oxt,
    uint4_t* __restrict__ ows, uint4_t* __restrict__ owt,
    float* __restrict__ stats, float* __restrict__ out) {
  const long XP = (long)BT * HD / 16;  // 16B pieces per X tensor
  const long WP = (long)VD * HD / 16;
  const long total = 2 * (XP + WP);
  const long i0 = blockIdx.x * 256L + threadIdx.x;
  if (i0 == 0) out[0] = 0.6931471805599453f;
  if (i0 < 2 * BT) stats[i0] = 0.f;
  for (long i = i0; i < total; i += gridDim.x * 256L) {
    const float* s; uint4_t* d; float scl; long j = i;
    if (j < XP) { s = xs; d = oxs; scl = 1.f; }
    else if ((j -= XP) < XP) { s = xt; d = oxt; scl = 1.f; }
    else if ((j -= XP) < WP) { s = ws; d = ows; scl = 64.f; }
    else { j -= WP; s = wt; d = owt; scl = 64.f; }
    // piece j -> k-block j>>2, sub-piece p=j&3; elem base e = block*64 + p*8
    const float* sp = s + ((j >> 2) * 64 + (j & 3) * 8);
    float4_t v0 = __builtin_nontemporal_load((const float4_t*)(sp));
    float4_t v1 = __builtin_nontemporal_load((const float4_t*)(sp + 4));
    float4_t v2 = __builtin_nontemporal_load((const float4_t*)(sp + 32));
    float4_t v3 = __builtin_nontemporal_load((const float4_t*)(sp + 36));
    uint4_t o;
    o.x = pk_fp8x4(v0.x * scl, v0.y * scl, v0.z * scl, v0.w * scl);
    o.y = pk_fp8x4(v1.x * scl, v1.y * scl, v1.z * scl, v1.w * scl);
    o.z = pk_fp8x4(v2.x * scl, v2.y * scl, v2.z * scl, v2.w * scl);
    o.w = pk_fp8x4(v3.x * scl, v3.y * scl, v3.z * scl, v3.w * scl);
    d[j] = o;
  }
}

// legacy swizzle for 128x128 fallback kernels
__device__ __forceinline__ int swz(int row) { return (row ^ (row >> 2)) & 3; }

// ---------------------------------------------------------------------------
// Legacy 128x128 tile (used by fallback ws paths) — unchanged, verified.
// ---------------------------------------------------------------------------
template <bool F32SRC>
__device__ __forceinline__ void ktile(const void* A, const void* B,
                                      float4_t (&acc)[4][4],
                                      unsigned short* As, unsigned short* Bs,
                                      int m0, int n0) {
  const int tid = threadIdx.x;
  const int lane = tid & 63;
  const int wave = tid >> 6;
  const int wm = wave >> 1, wn = wave & 1;
  const int r0 = tid >> 2, c0 = tid & 3;
  const int cg = c0 ^ swz(r0);
  const int row16 = lane & 15, kq = lane >> 4;
  const int kqs = kq ^ swz(row16);
  const int aoff = (wm * 64 + row16) * BK + kqs * 8;
  const int boff = (wn * 64 + row16) * BK + kqs * 8;
  const int lds0 = __builtin_amdgcn_readfirstlane(wave * 1024);
  const int lds1 = __builtin_amdgcn_readfirstlane(4096 + wave * 1024);

  const unsigned short* Ab = nullptr; const unsigned short* Bb = nullptr;
  const float* Af = nullptr; const float* Bf = nullptr;
  if constexpr (!F32SRC) {
    Ab = (const unsigned short*)A + (size_t)(m0 + r0) * HD + cg * 8;
    Bb = (const unsigned short*)B + (size_t)(n0 + r0) * HD + cg * 8;
  } else {
    Af = (const float*)A + (size_t)(m0 + r0) * HD + cg * 8;
    Bf = (const float*)B + (size_t)(n0 + r0) * HD + cg * 8;
  }

  for (int kb = 0; kb < HD / BK; ++kb) {
    const int ke = kb * BK;
    if constexpr (!F32SRC) {
      async_copy16(Ab + ke, (char*)As + lds0);
      async_copy16(Ab + (size_t)64 * HD + ke, (char*)As + lds1);
      async_copy16(Bb + ke, (char*)Bs + lds0);
      async_copy16(Bb + (size_t)64 * HD + ke, (char*)Bs + lds1);
    } else {
      short8_t hA0 = pack8(*(const float4_t*)(Af + ke), *(const float4_t*)(Af + ke + 4));
      short8_t hA1 = pack8(*(const float4_t*)(Af + (size_t)64 * HD + ke),
                           *(const float4_t*)(Af + (size_t)64 * HD + ke + 4));
      short8_t hB0 = pack8(*(const float4_t*)(Bf + ke), *(const float4_t*)(Bf + ke + 4));
      short8_t hB1 = pack8(*(const float4_t*)(Bf + (size_t)64 * HD + ke),
                           *(const float4_t*)(Bf + (size_t)64 * HD + ke + 4));
      *(short8_t*)((char*)As + tid * 16) = hA0;
      *(short8_t*)((char*)As + 4096 + tid * 16) = hA1;
      *(short8_t*)((char*)Bs + tid * 16) = hB0;
      *(short8_t*)((char*)Bs + 4096 + tid * 16) = hB1;
    }
    __syncthreads();
    short8_t af[4], bfv[4];
#pragma unroll
    for (int mi = 0; mi < 4; ++mi) af[mi] = *(const short8_t*)(As + aoff + mi * 16 * BK);
#pragma unroll
    for (int ni = 0; ni < 4; ++ni) bfv[ni] = *(const short8_t*)(Bs + boff + ni * 16 * BK);
#pragma unroll
    for (int mi = 0; mi < 4; ++mi)
#pragma unroll
      for (int ni = 0; ni < 4; ++ni)
        acc[mi][ni] = __builtin_amdgcn_mfma_f32_16x16x32_bf16(af[mi], bfv[ni], acc[mi][ni], 0, 0, 0);
    __syncthreads();
  }
}

// Pass 1 legacy (fallback paths): 128x128 tile.
template <bool F32SRC, bool STORE>
__global__ __launch_bounds__(256, 2) void gemm_pass1(
    const void* A0, const void* A1, const void* B0, const void* B1,
    float* __restrict__ rowsum, unsigned short* __restrict__ store) {
  __shared__ __align__(16) unsigned short As[BM * BK];
  __shared__ __align__(16) unsigned short Bs[BN * BK];
  const int m0 = blockIdx.x * BM;
  const int n0 = blockIdx.y * BN;
  const int z = blockIdx.z;
  const void* A = z ? A1 : A0;
  const void* B = z ? B1 : B0;
  float4_t acc[4][4] = {};
  ktile<F32SRC>(A, B, acc, As, Bs, m0, n0);

  const int tid = threadIdx.x;
  const int lane = tid & 63;
  const int wave = tid >> 6;
  const int wm = wave >> 1, wn = wave & 1;
  const int row16 = lane & 15, kq = lane >> 4;

  if constexpr (STORE) {
    unsigned short* st = store + (size_t)z * BT * VD;
#pragma unroll
    for (int mi = 0; mi < 4; ++mi)
#pragma unroll
      for (int r = 0; r < 4; ++r) {
        const size_t grow = (size_t)(m0 + wm * 64 + mi * 16 + kq * 4 + r);
        const size_t gc0 = (size_t)(n0 + wn * 64 + row16);
#pragma unroll
        for (int ni = 0; ni < 4; ++ni)
          st[grow * VD + gc0 + ni * 16] = f2bf(acc[mi][ni][r]);
      }
  }

  float* rs = rowsum + z * BT;
#pragma unroll
  for (int mi = 0; mi < 4; ++mi)
#pragma unroll
    for (int r = 0; r < 4; ++r) {
      float s = __expf(acc[mi][0][r]) + __expf(acc[mi][1][r]) +
                __expf(acc[mi][2][r]) + __expf(acc[mi][3][r]);
      s += __shfl_xor(s, 1);
      s += __shfl_xor(s, 2);
      s += __shfl_xor(s, 4);
      s += __shfl_xor(s, 8);
      if (row16 == 0) atomicAdd(&rs[m0 + wm * 64 + mi * 16 + kq * 4 + r], s);
    }
}

// ---------------------------------------------------------------------------
// 128x128 fp8 GEMM, v13 = v10 (ring-2, 3.6 blocks/CU, best measured: 808us)
// + NONTEMPORAL logit stores.
//  - v12 lesson: ring-3 counted vmcnt cost occupancy (45->34%) and LOST
//    (844 vs 808) -> at >=3 blocks/CU, co-residency already covers the
//    vmcnt(0) drain; T4 is null here. Reverted.
//  - New: FETCH_SIZE was 2.1 GB vs ~150 MB ideal (fp8 W+X fully L3-fit).
//    The 576 MB/dispatch streaming logit writes evict W/X from L2/L3 ->
//    14x HBM re-fetch. Logits are write-once/read-once -> nontemporal
//    stores keep them out of the caches; W/X stay L3-resident.
//    Gate: FETCH_SIZE < 1.0e6 KB.
// ---------------------------------------------------------------------------
constexpr int NKT8 = HD / 64;  // 32 K-tiles of 64

__global__ __launch_bounds__(256, 3) void gemm128_fp8_pass1(
    const unsigned char* __restrict__ fXs, const unsigned char* __restrict__ fXt,
    const unsigned char* __restrict__ fWs, const unsigned char* __restrict__ fWt,
    float* __restrict__ rowsum, unsigned short* __restrict__ store) {
  __shared__ __align__(16) unsigned char lds8[2 * 16384];  // 32 KiB

  const int z = blockIdx.y;
  const unsigned char* A = z ? fXt : fXs;
  const unsigned char* B = z ? fWt : fWs;

  // bijective XCD swizzle: 8000 wg/z, 8000 % 8 == 0, 1000 per XCD.
  const int o = blockIdx.x;
  const int s = (o & 7) * 1000 + (o >> 3);
  const int m0 = (s & 31) * 128;   // m fastest: same-XCD neighbors share W-panel
  const int n0 = (s >> 5) * 128;

  const int tid = threadIdx.x;
  const int lane = tid & 63;
  const int wave = tid >> 6;   // 0..3
  const int wm = wave >> 1;    // 0..1
  const int wn = wave & 1;     // 0..1
  const int row16 = lane & 15, kq = lane >> 4;
  const int rh = row16 >> 1;                        // 3-bit swizzle key (R&7)
  const int cA = (((row16 & 1) << 2) | kq) ^ rh;    // swizzled 16B chunk 0..7

  // Staging source map (inverse-swizzled; LDS dest linear).
  const int lr = lane >> 3, lc = lane & 7;
  const int cl = lc ^ lr;
  const int k16 = (cl & 3) * 16;
  const int mloc0 = (wave * 2 + 0) * 16 + 2 * lr + (cl >> 2);
  const int mloc1 = (wave * 2 + 1) * 16 + 2 * lr + (cl >> 2);
  const unsigned char* srcA0 = A + (size_t)(m0 + mloc0) * HD + k16;
  const unsigned char* srcA1 = A + (size_t)(m0 + mloc1) * HD + k16;
  const unsigned char* srcB0 = B + (size_t)(n0 + mloc0) * HD + k16;
  const unsigned char* srcB1 = B + (size_t)(n0 + mloc1) * HD + k16;
  const int stA0 = __builtin_amdgcn_readfirstlane((wave * 2 + 0) * 1024);
  const int stA1 = __builtin_amdgcn_readfirstlane((wave * 2 + 1) * 1024);

#define STAGE(ktv, sl)                                                   \
  do {                                                                   \
    char* _sb = (char*)lds8 + (sl) * 16384;                              \
    async_copy16(srcA0 + (size_t)(ktv) * 64, _sb + stA0);                \
    async_copy16(srcA1 + (size_t)(ktv) * 64, _sb + stA1);                \
    async_copy16(srcB0 + (size_t)(ktv) * 64, _sb + 8192 + stA0);         \
    async_copy16(srcB1 + (size_t)(ktv) * 64, _sb + 8192 + stA1);         \
  } while (0)

  // Prologue: stage tile 0, drain, barrier.
  STAGE(0, 0);
  asm volatile("s_waitcnt vmcnt(0)" ::: "memory");
  __builtin_amdgcn_s_barrier();

  float4_t acc[4][4] = {};
  // Byte offsets of the lane's 16B fragment (both k-halves).
  const int aoff = (wm * 32 + rh) * 128 + cA * 16;
  const int boff = (wn * 32 + rh) * 128 + cA * 16;

#pragma unroll 1
  for (int kt = 0; kt < NKT8; ++kt) {
    __builtin_amdgcn_sched_barrier(0);  // nothing crosses the K-tile boundary
    const int ktS = (kt + 1 > NKT8 - 1) ? NKT8 - 1 : kt + 1;
    STAGE(ktS, (kt + 1) & 1);  // tail: dead rewrite into the other slot, benign

    const unsigned char* Asl = lds8 + (kt & 1) * 16384;
    const unsigned char* Bsl = Asl + 8192;
    long2_t a[4], b[4];
#pragma unroll
    for (int mi = 0; mi < 4; ++mi) a[mi] = *(const long2_t*)(Asl + aoff + mi * 1024);
#pragma unroll
    for (int ni = 0; ni < 4; ++ni) b[ni] = *(const long2_t*)(Bsl + boff + ni * 1024);

    __builtin_amdgcn_s_setprio(1);
#pragma unroll
    for (int mi = 0; mi < 4; ++mi)
#pragma unroll
      for (int ni = 0; ni < 4; ++ni)
        acc[mi][ni] = __builtin_amdgcn_mfma_f32_16x16x32_fp8_fp8(a[mi].x, b[ni].x, acc[mi][ni], 0, 0, 0);
#pragma unroll
    for (int mi = 0; mi < 4; ++mi)
#pragma unroll
      for (int ni = 0; ni < 4; ++ni)
        acc[mi][ni] = __builtin_amdgcn_mfma_f32_16x16x32_fp8_fp8(a[mi].y, b[ni].y, acc[mi][ni], 0, 0, 0);
    __builtin_amdgcn_s_setprio(0);

    // drain this body's staging (next tile); co-resident blocks cover this.
    asm volatile("s_waitcnt vmcnt(0)" ::: "memory");
    __builtin_amdgcn_s_barrier();
  }
#undef STAGE

  // Epilogue: undo the W 2^6 prescale, store bf16 logits (NONTEMPORAL:
  // write-once data must not evict the L3-resident W/X panels) + per-row
  // sum(exp).
  const float SCL = 0.015625f;  // 1/64
  unsigned short* st = store + (size_t)z * BT * VD;
  float* rs = rowsum + z * BT;
#pragma unroll
  for (int mi = 0; mi < 4; ++mi)
#pragma unroll
    for (int r = 0; r < 4; ++r) {
      const size_t grow = (size_t)(m0 + wm * 64 + mi * 16 + kq * 4 + r);
      const size_t gc0 = (size_t)(n0 + wn * 64 + row16);
      float zv[4];
#pragma unroll
      for (int ni = 0; ni < 4; ++ni) {
        zv[ni] = acc[mi][ni][r] * SCL;
        __builtin_nontemporal_store((unsigned short)f2bf(zv[ni]),
                                    &st[grow * VD + gc0 + ni * 16]);
      }
      float ssum = __expf(zv[0]) + __expf(zv[1]) + __expf(zv[2]) + __expf(zv[3]);
      ssum += __shfl_xor(ssum, 1);
      ssum += __shfl_xor(ssum, 2);
      ssum += __shfl_xor(ssum, 4);
      ssum += __shfl_xor(ssum, 8);
      if (row16 == 0) atomicAdd(&rs[grow], ssum);
    }
}

// stats[i] = log(sum_exp) -> LSE; thread 0 seeds out with +ln2. Used by the
// recompute fallback paths only.
__global__ __launch_bounds__(256) void lse_fix(float* __restrict__ stats,
                                               float* __restrict__ out) {
  const int i = blockIdx.x * 256 + threadIdx.x;
  if (i < 2 * BT) stats[i] = __logf(stats[i]);
  if (i == 0) out[0] = 0.6931471805599453f;
}

// Seed-only kernel (MID fallback path; best path seeds in cast_all_fp8i).
__global__ void seed_out(float* __restrict__ out) {
  out[0] = 0.6931471805599453f;
}

// Pass 2 (materialized path): JSD terms from stored bf16 logits; one block per
// row. Takes RAW exp-sums and computes the LSE log inline. Logits are read
// ONCE -> nontemporal loads.
__global__ __launch_bounds__(256) void loss_from_blogits(
    const ushort8_t* __restrict__ zs, const ushort8_t* __restrict__ zt,
    const float* __restrict__ rs, float* __restrict__ out) {
  const int row = blockIdx.x;
  const float es = __logf(rs[row]), et = __logf(rs[BT + row]);
  const ushort8_t* ps = zs + (size_t)row * (VD / 8);
  const ushort8_t* pt = zt + (size_t)row * (VD / 8);
  float local = 0.f;
  for (int i = threadIdx.x; i < VD / 8; i += 256) {
    const ushort8_t a = __builtin_nontemporal_load(&ps[i]);
    const ushort8_t b = __builtin_nontemporal_load(&pt[i]);
#pragma unroll
    for (int c = 0; c < 8; ++c) {
      const float ls = bf2f(a[c]) - es, lt = bf2f(b[c]) - et;
      const float p = __expf(ls), q = __expf(lt);
      local += p * ls + q * lt - (p + q) * __logf(p + q);
    }
  }
  local += __shfl_xor(local, 1);
  local += __shfl_xor(local, 2);
  local += __shfl_xor(local, 4);
  local += __shfl_xor(local, 8);
  local += __shfl_xor(local, 16);
  local += __shfl_xor(local, 32);
  __shared__ float red[4];
  const int lane = threadIdx.x & 63, wave = threadIdx.x >> 6;
  if (lane == 0) red[wave] = local;
  __syncthreads();
  if (threadIdx.x == 0)
    atomicAdd(out, (red[0] + red[1] + red[2] + red[3]) * (0.5f / BT));
}

// Pass 2 (recompute fallback): both GEMM tiles then joint JSD terms.
template <bool F32SRC>
__global__ __launch_bounds__(256, 2) void gemm_loss(
    const void* Asg, const void* Bsg, const void* Atg, const void* Btg,
    const float* __restrict__ lse, float* __restrict__ out) {
  __shared__ __align__(16) unsigned short As[BM * BK];
  __shared__ __align__(16) unsigned short Bs[BN * BK];
  __shared__ float red[4];
  const int m0 = blockIdx.x * BM;
  const int n0 = blockIdx.y * BN;
  float4_t acc_s[4][4] = {};
  ktile<F32SRC>(Asg, Bsg, acc_s, As, Bs, m0, n0);
  float4_t acc_t[4][4] = {};
  ktile<F32SRC>(Atg, Btg, acc_t, As, Bs, m0, n0);

  const int tid = threadIdx.x;
  const int lane = tid & 63;
  const int wave = tid >> 6;
  const int wm = wave >> 1;
  const int kq = lane >> 4;

  float local = 0.f;
#pragma unroll
  for (int mi = 0; mi < 4; ++mi)
#pragma unroll
    for (int r = 0; r < 4; ++r) {
      const int grow = m0 + wm * 64 + mi * 16 + kq * 4 + r;
      const float es = lse[grow], et = lse[BT + grow];
#pragma unroll
      for (int ni = 0; ni < 4; ++ni) {
        const float ls = acc_s[mi][ni][r] - es;
        const float lt = acc_t[mi][ni][r] - et;
        const float p = __expf(ls), q = __expf(lt);
        local += p * ls + q * lt - (p + q) * __logf(p + q);
      }
    }
  local += __shfl_xor(local, 1);
  local += __shfl_xor(local, 2);
  local += __shfl_xor(local, 4);
  local += __shfl_xor(local, 8);
  local += __shfl_xor(local, 16);
  local += __shfl_xor(local, 32);
  if (lane == 0) red[wave] = local;
  __syncthreads();
  if (tid == 0) atomicAdd(out, (red[0] + red[1] + red[2] + red[3]) * (0.5f / BT));
}

extern "C" void kernel_launch(void* const* d_in, const int* in_sizes, int n_in,
                              void* d_out, int out_size, void* d_ws, size_t ws_size,
                              hipStream_t stream) {
  const float* Xs = (const float*)d_in[0];
  const float* Xt = (const float*)d_in[1];
  const float* Ws = (const float*)d_in[2];
  const float* Wt = (const float*)d_in[3];
  float* out = (float*)d_out;
  char* ws = (char*)d_ws;

  const size_t STATS_B = (size_t)2 * BT * sizeof(float);          // 32 KB
  const size_t XB8 = (size_t)BT * HD;                             // fp8 X (8 MB)
  const size_t WB8 = (size_t)VD * HD;                             // fp8 W (65.5 MB)
  const size_t XB = (size_t)BT * HD * 2;                          // bf16 X
  const size_t WB = (size_t)VD * HD * 2;                          // bf16 W
  const size_t LOGIT_B = (size_t)2 * BT * VD * 2;                 // bf16 logits (s+t)
  const size_t FP8_NEED = STATS_B + 2 * XB8 + 2 * WB8 + LOGIT_B;  // ~672 MB
  const size_t PRECAST_NEED = STATS_B + 2 * XB + 2 * WB;          // ~296 MB
  const size_t MID_NEED = STATS_B + LOGIT_B;                      // ~524 MB

  float* stats = (float*)ws;

  const dim3 blk(256);
  const dim3 g1(BT / BM, VD / BN, 2);
  const dim3 g2(BT / BM, VD / BN, 1);
  const int XN4 = BT * HD / 4;
  const int WN4 = VD * HD / 4;

  if (ws_size >= FP8_NEED) {
    // fp8 GEMM path: cast to k-interleaved e4m3 (W prescaled x64; also
    // zeroes stats + seeds out), 128^2 fp8 ring-2 pipeline with NT logit
    // stores, loss from bf16 logits (NT loads).
    unsigned char* fXs = (unsigned char*)(ws + STATS_B);
    unsigned char* fXt = fXs + XB8;
    unsigned char* fWs = fXt + XB8;
    unsigned char* fWt = fWs + WB8;
    unsigned short* logits = (unsigned short*)(ws + STATS_B + 2 * XB8 + 2 * WB8);
    cast_all_fp8i<<<dim3(2048), blk, 0, stream>>>(
        Xs, Xt, Ws, Wt,
        (uint4_t*)fXs, (uint4_t*)fXt, (uint4_t*)fWs, (uint4_t*)fWt, stats, out);
    gemm128_fp8_pass1<<<dim3((BT / 128) * (VD / 128), 2), dim3(256), 0, stream>>>(
        fXs, fXt, fWs, fWt, stats, logits);
    loss_from_blogits<<<dim3(BT), blk, 0, stream>>>(
        (const ushort8_t*)logits,
        (const ushort8_t*)(logits + (size_t)BT * VD), stats, out);
  } else if (ws_size >= MID_NEED) {
    // no precast: stage f32->bf16 on the fly, materialize bf16 logits
    unsigned short* logits = (unsigned short*)(ws + STATS_B);
    hipMemsetAsync(stats, 0, STATS_B, stream);
    gemm_pass1<true, true><<<g1, blk, 0, stream>>>(Xs, Xt, Ws, Wt, stats, logits);
    seed_out<<<dim3(1), dim3(1), 0, stream>>>(out);
    loss_from_blogits<<<dim3(BT), blk, 0, stream>>>(
        (const ushort8_t*)logits,
        (const ushort8_t*)(logits + (size_t)BT * VD), stats, out);
  } else if (ws_size >= PRECAST_NEED) {
    // precast bf16, recompute logits in pass 2
    unsigned short* bXs = (unsigned short*)(ws + STATS_B);
    unsigned short* bXt = bXs + (size_t)BT * HD;
    unsigned short* bWs = bXt + (size_t)BT * HD;
    unsigned short* bWt = bWs + (size_t)VD * HD;
    hipMemsetAsync(stats, 0, STATS_B, stream);
    cast_f32_to_bf16<<<dim3(512), blk, 0, stream>>>((const float4_t*)Xs, (short4_t*)bXs, XN4);
    cast_f32_to_bf16<<<dim3(512), blk, 0, stream>>>((const float4_t*)Xt, (short4_t*)bXt, XN4);
    cast_f32_to_bf16<<<dim3(2048), blk, 0, stream>>>((const float4_t*)Ws, (short4_t*)bWs, WN4);
    cast_f32_to_bf16<<<dim3(2048), blk, 0, stream>>>((const float4_t*)Wt, (short4_t*)bWt, WN4);
    gemm_pass1<false, false><<<g1, blk, 0, stream>>>(bXs, bXt, bWs, bWt, stats, nullptr);
    lse_fix<<<dim3(32), blk, 0, stream>>>(stats, out);
    gemm_loss<false><<<g2, blk, 0, stream>>>(bXs, bWs, bXt, bWt, stats, out);
  } else {
    // minimal-ws fallback: everything on the fly (needs only 32 KB)
    hipMemsetAsync(stats, 0, STATS_B, stream);
    gemm_pass1<true, false><<<g1, blk, 0, stream>>>(Xs, Xt, Ws, Wt, stats, nullptr);
    lse_fix<<<dim3(32), blk, 0, stream>>>(stats, out);
    gemm_loss<true><<<g2, blk, 0, stream>>>(Xs, Ws, Xt, Wt, stats, out);
  }
  (void)in_sizes; (void)n_in; (void)out_size;
}

// Round 14
// 1305.130 us; speedup vs baseline: 1.1520x; 1.0845x over previous
//
#include <hip/hip_runtime.h>
#include <cstdint>

#define BT 4096
#define HD 2048
#define VD 32000

typedef __attribute__((ext_vector_type(4))) float float4_t;
typedef __attribute__((ext_vector_type(4))) short short4_t;
typedef __attribute__((ext_vector_type(8))) short short8_t;
typedef __attribute__((ext_vector_type(8))) unsigned short ushort8_t;
typedef __attribute__((ext_vector_type(2))) long long2_t;
typedef __attribute__((ext_vector_type(4))) unsigned int uint4_t;

constexpr int BM = 128, BN = 128, BK = 32;

// f32 -> bf16 round-to-nearest-even (inputs are normal, no NaN handling needed)
__device__ __forceinline__ unsigned short f2bf(float f) {
  unsigned u = __float_as_uint(f);
  u += 0x7FFFu + ((u >> 16) & 1u);
  return (unsigned short)(u >> 16);
}

__device__ __forceinline__ float bf2f(unsigned short h) {
  return __uint_as_float((unsigned)h << 16);
}

__device__ __forceinline__ short8_t pack8(float4_t a, float4_t b) {
  short8_t h;
  h[0] = (short)f2bf(a.x); h[1] = (short)f2bf(a.y);
  h[2] = (short)f2bf(a.z); h[3] = (short)f2bf(a.w);
  h[4] = (short)f2bf(b.x); h[5] = (short)f2bf(b.y);
  h[6] = (short)f2bf(b.z); h[7] = (short)f2bf(b.w);
  return h;
}

// async global->LDS, 16B per lane; LDS dest is wave-uniform base + lane*16.
__device__ __forceinline__ void async_copy16(const void* g, void* l) {
  __builtin_amdgcn_global_load_lds(
      (__attribute__((address_space(1))) void*)(uintptr_t)(g),
      (__attribute__((address_space(3))) void*)(uint32_t)(uintptr_t)(l),
      16, 0, 0);
}

__global__ __launch_bounds__(256) void cast_f32_to_bf16(
    const float4_t* __restrict__ in, short4_t* __restrict__ out, int n4) {
  for (int i = blockIdx.x * 256 + threadIdx.x; i < n4; i += gridDim.x * 256) {
    float4_t v = in[i];
    short4_t o;
    o.x = (short)f2bf(v.x); o.y = (short)f2bf(v.y);
    o.z = (short)f2bf(v.z); o.w = (short)f2bf(v.w);
    out[i] = o;
  }
}

__device__ __forceinline__ unsigned int pk_fp8x4(float a, float b, float c, float d) {
  int p = __builtin_amdgcn_cvt_pk_fp8_f32(a, b, 0, false);
  p = __builtin_amdgcn_cvt_pk_fp8_f32(c, d, p, true);
  return (unsigned int)p;
}

// Fused f32 -> fp8(e4m3) cast for all four inputs, writing a K-INTERLEAVED
// layout: each 64-elem k-block is stored as 4 x 16B pieces, piece p holding
// logical k {p*8..p*8+7} then {32+p*8..32+p*8+7}. Piece p is exactly MFMA
// lane kq=p's operand pair for the K=64 tile -> the GEMM can read one
// ds_read_b128 per fragment (the verified conflict-free pattern).
// W is prescaled by 2^6 (exact; N(0,0.02^2) would hit e4m3 denormals);
// the GEMM epilogue multiplies acc by 1/64. Thread 0 seeds out[0] = ln2.
// Also zeroes the rowsum stats (replaces the hipMemsetAsync launch).
// f32 inputs are read ONCE -> nontemporal loads (keep L2/L3 for the GEMM).
__global__ __launch_bounds__(256) void cast_all_fp8i(
    const float* __restrict__ xs, const float* __restrict__ xt,
    const float* __restrict__ ws, const float* __restrict__ wt,
    uint4_t* __restrict__ oxs, uint4_t* __restrict__ oxt,
    uint4_t* __restrict__ ows, uint4_t* __restrict__ owt,
    float* __restrict__ stats, float* __restrict__ out) {
  const long XP = (long)BT * HD / 16;  // 16B pieces per X tensor
  const long WP = (long)VD * HD / 16;
  const long total = 2 * (XP + WP);
  const long i0 = blockIdx.x * 256L + threadIdx.x;
  if (i0 == 0) out[0] = 0.6931471805599453f;
  if (i0 < 2 * BT) stats[i0] = 0.f;
  for (long i = i0; i < total; i += gridDim.x * 256L) {
    const float* s; uint4_t* d; float scl; long j = i;
    if (j < XP) { s = xs; d = oxs; scl = 1.f; }
    else if ((j -= XP) < XP) { s = xt; d = oxt; scl = 1.f; }
    else if ((j -= XP) < WP) { s = ws; d = ows; scl = 64.f; }
    else { j -= WP; s = wt; d = owt; scl = 64.f; }
    // piece j -> k-block j>>2, sub-piece p=j&3; elem base e = block*64 + p*8
    const float* sp = s + ((j >> 2) * 64 + (j & 3) * 8);
    float4_t v0 = __builtin_nontemporal_load((const float4_t*)(sp));
    float4_t v1 = __builtin_nontemporal_load((const float4_t*)(sp + 4));
    float4_t v2 = __builtin_nontemporal_load((const float4_t*)(sp + 32));
    float4_t v3 = __builtin_nontemporal_load((const float4_t*)(sp + 36));
    uint4_t o;
    o.x = pk_fp8x4(v0.x * scl, v0.y * scl, v0.z * scl, v0.w * scl);
    o.y = pk_fp8x4(v1.x * scl, v1.y * scl, v1.z * scl, v1.w * scl);
    o.z = pk_fp8x4(v2.x * scl, v2.y * scl, v2.z * scl, v2.w * scl);
    o.w = pk_fp8x4(v3.x * scl, v3.y * scl, v3.z * scl, v3.w * scl);
    d[j] = o;
  }
}

// legacy swizzle for 128x128 fallback kernels
__device__ __forceinline__ int swz(int row) { return (row ^ (row >> 2)) & 3; }

// ---------------------------------------------------------------------------
// Legacy 128x128 tile (used by fallback ws paths) — unchanged, verified.
// ---------------------------------------------------------------------------
template <bool F32SRC>
__device__ __forceinline__ void ktile(const void* A, const void* B,
                                      float4_t (&acc)[4][4],
                                      unsigned short* As, unsigned short* Bs,
                                      int m0, int n0) {
  const int tid = threadIdx.x;
  const int lane = tid & 63;
  const int wave = tid >> 6;
  const int wm = wave >> 1, wn = wave & 1;
  const int r0 = tid >> 2, c0 = tid & 3;
  const int cg = c0 ^ swz(r0);
  const int row16 = lane & 15, kq = lane >> 4;
  const int kqs = kq ^ swz(row16);
  const int aoff = (wm * 64 + row16) * BK + kqs * 8;
  const int boff = (wn * 64 + row16) * BK + kqs * 8;
  const int lds0 = __builtin_amdgcn_readfirstlane(wave * 1024);
  const int lds1 = __builtin_amdgcn_readfirstlane(4096 + wave * 1024);

  const unsigned short* Ab = nullptr; const unsigned short* Bb = nullptr;
  const float* Af = nullptr; const float* Bf = nullptr;
  if constexpr (!F32SRC) {
    Ab = (const unsigned short*)A + (size_t)(m0 + r0) * HD + cg * 8;
    Bb = (const unsigned short*)B + (size_t)(n0 + r0) * HD + cg * 8;
  } else {
    Af = (const float*)A + (size_t)(m0 + r0) * HD + cg * 8;
    Bf = (const float*)B + (size_t)(n0 + r0) * HD + cg * 8;
  }

  for (int kb = 0; kb < HD / BK; ++kb) {
    const int ke = kb * BK;
    if constexpr (!F32SRC) {
      async_copy16(Ab + ke, (char*)As + lds0);
      async_copy16(Ab + (size_t)64 * HD + ke, (char*)As + lds1);
      async_copy16(Bb + ke, (char*)Bs + lds0);
      async_copy16(Bb + (size_t)64 * HD + ke, (char*)Bs + lds1);
    } else {
      short8_t hA0 = pack8(*(const float4_t*)(Af + ke), *(const float4_t*)(Af + ke + 4));
      short8_t hA1 = pack8(*(const float4_t*)(Af + (size_t)64 * HD + ke),
                           *(const float4_t*)(Af + (size_t)64 * HD + ke + 4));
      short8_t hB0 = pack8(*(const float4_t*)(Bf + ke), *(const float4_t*)(Bf + ke + 4));
      short8_t hB1 = pack8(*(const float4_t*)(Bf + (size_t)64 * HD + ke),
                           *(const float4_t*)(Bf + (size_t)64 * HD + ke + 4));
      *(short8_t*)((char*)As + tid * 16) = hA0;
      *(short8_t*)((char*)As + 4096 + tid * 16) = hA1;
      *(short8_t*)((char*)Bs + tid * 16) = hB0;
      *(short8_t*)((char*)Bs + 4096 + tid * 16) = hB1;
    }
    __syncthreads();
    short8_t af[4], bfv[4];
#pragma unroll
    for (int mi = 0; mi < 4; ++mi) af[mi] = *(const short8_t*)(As + aoff + mi * 16 * BK);
#pragma unroll
    for (int ni = 0; ni < 4; ++ni) bfv[ni] = *(const short8_t*)(Bs + boff + ni * 16 * BK);
#pragma unroll
    for (int mi = 0; mi < 4; ++mi)
#pragma unroll
      for (int ni = 0; ni < 4; ++ni)
        acc[mi][ni] = __builtin_amdgcn_mfma_f32_16x16x32_bf16(af[mi], bfv[ni], acc[mi][ni], 0, 0, 0);
    __syncthreads();
  }
}

// Pass 1 legacy (fallback paths): 128x128 tile.
template <bool F32SRC, bool STORE>
__global__ __launch_bounds__(256, 2) void gemm_pass1(
    const void* A0, const void* A1, const void* B0, const void* B1,
    float* __restrict__ rowsum, unsigned short* __restrict__ store) {
  __shared__ __align__(16) unsigned short As[BM * BK];
  __shared__ __align__(16) unsigned short Bs[BN * BK];
  const int m0 = blockIdx.x * BM;
  const int n0 = blockIdx.y * BN;
  const int z = blockIdx.z;
  const void* A = z ? A1 : A0;
  const void* B = z ? B1 : B0;
  float4_t acc[4][4] = {};
  ktile<F32SRC>(A, B, acc, As, Bs, m0, n0);

  const int tid = threadIdx.x;
  const int lane = tid & 63;
  const int wave = tid >> 6;
  const int wm = wave >> 1, wn = wave & 1;
  const int row16 = lane & 15, kq = lane >> 4;

  if constexpr (STORE) {
    unsigned short* st = store + (size_t)z * BT * VD;
#pragma unroll
    for (int mi = 0; mi < 4; ++mi)
#pragma unroll
      for (int r = 0; r < 4; ++r) {
        const size_t grow = (size_t)(m0 + wm * 64 + mi * 16 + kq * 4 + r);
        const size_t gc0 = (size_t)(n0 + wn * 64 + row16);
#pragma unroll
        for (int ni = 0; ni < 4; ++ni)
          st[grow * VD + gc0 + ni * 16] = f2bf(acc[mi][ni][r]);
      }
  }

  float* rs = rowsum + z * BT;
#pragma unroll
  for (int mi = 0; mi < 4; ++mi)
#pragma unroll
    for (int r = 0; r < 4; ++r) {
      float s = __expf(acc[mi][0][r]) + __expf(acc[mi][1][r]) +
                __expf(acc[mi][2][r]) + __expf(acc[mi][3][r]);
      s += __shfl_xor(s, 1);
      s += __shfl_xor(s, 2);
      s += __shfl_xor(s, 4);
      s += __shfl_xor(s, 8);
      if (row16 == 0) atomicAdd(&rs[m0 + wm * 64 + mi * 16 + kq * 4 + r], s);
    }
}

// ---------------------------------------------------------------------------
// 128x128 fp8 GEMM, v14 = v10 core (ring-2, 3.6 blocks/CU, vmcnt(0) covered
// by co-residency) + BAND-MAJOR XCD-CONTIGUOUS tile order:
//  - Round-13 evidence: FETCH_SIZE 2.07 GB vs ~150 MB ideal (14x re-fetch).
//    Old m-fastest order made each XCD's 1000 blocks sweep ALL X panels
//    (16 MB both z) against a 4 MB L2 every 32 blocks, and the 524 MB logit
//    stream flushes L3 -> X re-fetched from HBM ~30x.
//  - New order: each XCD owns a contiguous 8m x 125n region; m-fastest
//    within the 8-m band. Band X (2 MB/z) stays L2-resident across all 125
//    n-steps; each W panel is consumed by 8 consecutive blocks.
//    Ideal fetch: X<=32 MB + W<=524 MB. Gate: FETCH_SIZE < 1.0e6 KB.
//  - Round-13 NT-store lesson: 2-byte NT stores defeat write-combining
//    (WRITE_SIZE 576->730 MB) -> reverted to regular stores.
// ---------------------------------------------------------------------------
constexpr int NKT8 = HD / 64;  // 32 K-tiles of 64

__global__ __launch_bounds__(256, 3) void gemm128_fp8_pass1(
    const unsigned char* __restrict__ fXs, const unsigned char* __restrict__ fXt,
    const unsigned char* __restrict__ fWs, const unsigned char* __restrict__ fWt,
    float* __restrict__ rowsum, unsigned short* __restrict__ store) {
  __shared__ __align__(16) unsigned char lds8[2 * 16384];  // 32 KiB

  const int z = blockIdx.y;
  const unsigned char* A = z ? fXt : fXs;
  const unsigned char* B = z ? fWt : fWs;

  // Band-major XCD-contiguous order: XCD x gets s_lin in [1000x, 1000x+1000);
  // band = s_lin/2000 (8 m-tiles), within band m-fastest, n sweeps.
  const int o = blockIdx.x;
  const int s_lin = (o & 7) * 1000 + (o >> 3);
  const int band = s_lin / 2000;        // 0..3
  const int r = s_lin % 2000;           // 0..1999
  const int m0 = (band * 8 + (r & 7)) * 128;
  const int n0 = (r >> 3) * 128;        // 0..249

  const int tid = threadIdx.x;
  const int lane = tid & 63;
  const int wave = tid >> 6;   // 0..3
  const int wm = wave >> 1;    // 0..1
  const int wn = wave & 1;     // 0..1
  const int row16 = lane & 15, kq = lane >> 4;
  const int rh = row16 >> 1;                        // 3-bit swizzle key (R&7)
  const int cA = (((row16 & 1) << 2) | kq) ^ rh;    // swizzled 16B chunk 0..7

  // Staging source map (inverse-swizzled; LDS dest linear).
  const int lr = lane >> 3, lc = lane & 7;
  const int cl = lc ^ lr;
  const int k16 = (cl & 3) * 16;
  const int mloc0 = (wave * 2 + 0) * 16 + 2 * lr + (cl >> 2);
  const int mloc1 = (wave * 2 + 1) * 16 + 2 * lr + (cl >> 2);
  const unsigned char* srcA0 = A + (size_t)(m0 + mloc0) * HD + k16;
  const unsigned char* srcA1 = A + (size_t)(m0 + mloc1) * HD + k16;
  const unsigned char* srcB0 = B + (size_t)(n0 + mloc0) * HD + k16;
  const unsigned char* srcB1 = B + (size_t)(n0 + mloc1) * HD + k16;
  const int stA0 = __builtin_amdgcn_readfirstlane((wave * 2 + 0) * 1024);
  const int stA1 = __builtin_amdgcn_readfirstlane((wave * 2 + 1) * 1024);

#define STAGE(ktv, sl)                                                   \
  do {                                                                   \
    char* _sb = (char*)lds8 + (sl) * 16384;                              \
    async_copy16(srcA0 + (size_t)(ktv) * 64, _sb + stA0);                \
    async_copy16(srcA1 + (size_t)(ktv) * 64, _sb + stA1);                \
    async_copy16(srcB0 + (size_t)(ktv) * 64, _sb + 8192 + stA0);         \
    async_copy16(srcB1 + (size_t)(ktv) * 64, _sb + 8192 + stA1);         \
  } while (0)

  // Prologue: stage tile 0, drain, barrier.
  STAGE(0, 0);
  asm volatile("s_waitcnt vmcnt(0)" ::: "memory");
  __builtin_amdgcn_s_barrier();

  float4_t acc[4][4] = {};
  // Byte offsets of the lane's 16B fragment (both k-halves).
  const int aoff = (wm * 32 + rh) * 128 + cA * 16;
  const int boff = (wn * 32 + rh) * 128 + cA * 16;

#pragma unroll 1
  for (int kt = 0; kt < NKT8; ++kt) {
    __builtin_amdgcn_sched_barrier(0);  // nothing crosses the K-tile boundary
    const int ktS = (kt + 1 > NKT8 - 1) ? NKT8 - 1 : kt + 1;
    STAGE(ktS, (kt + 1) & 1);  // tail: dead rewrite into the other slot, benign

    const unsigned char* Asl = lds8 + (kt & 1) * 16384;
    const unsigned char* Bsl = Asl + 8192;
    long2_t a[4], b[4];
#pragma unroll
    for (int mi = 0; mi < 4; ++mi) a[mi] = *(const long2_t*)(Asl + aoff + mi * 1024);
#pragma unroll
    for (int ni = 0; ni < 4; ++ni) b[ni] = *(const long2_t*)(Bsl + boff + ni * 1024);

    __builtin_amdgcn_s_setprio(1);
#pragma unroll
    for (int mi = 0; mi < 4; ++mi)
#pragma unroll
      for (int ni = 0; ni < 4; ++ni)
        acc[mi][ni] = __builtin_amdgcn_mfma_f32_16x16x32_fp8_fp8(a[mi].x, b[ni].x, acc[mi][ni], 0, 0, 0);
#pragma unroll
    for (int mi = 0; mi < 4; ++mi)
#pragma unroll
      for (int ni = 0; ni < 4; ++ni)
        acc[mi][ni] = __builtin_amdgcn_mfma_f32_16x16x32_fp8_fp8(a[mi].y, b[ni].y, acc[mi][ni], 0, 0, 0);
    __builtin_amdgcn_s_setprio(0);

    // drain this body's staging (next tile); co-resident blocks cover this.
    asm volatile("s_waitcnt vmcnt(0)" ::: "memory");
    __builtin_amdgcn_s_barrier();
  }
#undef STAGE

  // Epilogue: undo the W 2^6 prescale, store bf16 logits + per-row sum(exp).
  const float SCL = 0.015625f;  // 1/64
  unsigned short* st = store + (size_t)z * BT * VD;
  float* rs = rowsum + z * BT;
#pragma unroll
  for (int mi = 0; mi < 4; ++mi)
#pragma unroll
    for (int r2 = 0; r2 < 4; ++r2) {
      const size_t grow = (size_t)(m0 + wm * 64 + mi * 16 + kq * 4 + r2);
      const size_t gc0 = (size_t)(n0 + wn * 64 + row16);
      float zv[4];
#pragma unroll
      for (int ni = 0; ni < 4; ++ni) {
        zv[ni] = acc[mi][ni][r2] * SCL;
        st[grow * VD + gc0 + ni * 16] = f2bf(zv[ni]);
      }
      float ssum = __expf(zv[0]) + __expf(zv[1]) + __expf(zv[2]) + __expf(zv[3]);
      ssum += __shfl_xor(ssum, 1);
      ssum += __shfl_xor(ssum, 2);
      ssum += __shfl_xor(ssum, 4);
      ssum += __shfl_xor(ssum, 8);
      if (row16 == 0) atomicAdd(&rs[grow], ssum);
    }
}

// stats[i] = log(sum_exp) -> LSE; thread 0 seeds out with +ln2. Used by the
// recompute fallback paths only.
__global__ __launch_bounds__(256) void lse_fix(float* __restrict__ stats,
                                               float* __restrict__ out) {
  const int i = blockIdx.x * 256 + threadIdx.x;
  if (i < 2 * BT) stats[i] = __logf(stats[i]);
  if (i == 0) out[0] = 0.6931471805599453f;
}

// Seed-only kernel (MID fallback path; best path seeds in cast_all_fp8i).
__global__ void seed_out(float* __restrict__ out) {
  out[0] = 0.6931471805599453f;
}

// Pass 2 (materialized path): JSD terms from stored bf16 logits; one block per
// row. Takes RAW exp-sums and computes the LSE log inline. Logits are read
// ONCE -> nontemporal loads.
__global__ __launch_bounds__(256) void loss_from_blogits(
    const ushort8_t* __restrict__ zs, const ushort8_t* __restrict__ zt,
    const float* __restrict__ rs, float* __restrict__ out) {
  const int row = blockIdx.x;
  const float es = __logf(rs[row]), et = __logf(rs[BT + row]);
  const ushort8_t* ps = zs + (size_t)row * (VD / 8);
  const ushort8_t* pt = zt + (size_t)row * (VD / 8);
  float local = 0.f;
  for (int i = threadIdx.x; i < VD / 8; i += 256) {
    const ushort8_t a = __builtin_nontemporal_load(&ps[i]);
    const ushort8_t b = __builtin_nontemporal_load(&pt[i]);
#pragma unroll
    for (int c = 0; c < 8; ++c) {
      const float ls = bf2f(a[c]) - es, lt = bf2f(b[c]) - et;
      const float p = __expf(ls), q = __expf(lt);
      local += p * ls + q * lt - (p + q) * __logf(p + q);
    }
  }
  local += __shfl_xor(local, 1);
  local += __shfl_xor(local, 2);
  local += __shfl_xor(local, 4);
  local += __shfl_xor(local, 8);
  local += __shfl_xor(local, 16);
  local += __shfl_xor(local, 32);
  __shared__ float red[4];
  const int lane = threadIdx.x & 63, wave = threadIdx.x >> 6;
  if (lane == 0) red[wave] = local;
  __syncthreads();
  if (threadIdx.x == 0)
    atomicAdd(out, (red[0] + red[1] + red[2] + red[3]) * (0.5f / BT));
}

// Pass 2 (recompute fallback): both GEMM tiles then joint JSD terms.
template <bool F32SRC>
__global__ __launch_bounds__(256, 2) void gemm_loss(
    const void* Asg, const void* Bsg, const void* Atg, const void* Btg,
    const float* __restrict__ lse, float* __restrict__ out) {
  __shared__ __align__(16) unsigned short As[BM * BK];
  __shared__ __align__(16) unsigned short Bs[BN * BK];
  __shared__ float red[4];
  const int m0 = blockIdx.x * BM;
  const int n0 = blockIdx.y * BN;
  float4_t acc_s[4][4] = {};
  ktile<F32SRC>(Asg, Bsg, acc_s, As, Bs, m0, n0);
  float4_t acc_t[4][4] = {};
  ktile<F32SRC>(Atg, Btg, acc_t, As, Bs, m0, n0);

  const int tid = threadIdx.x;
  const int lane = tid & 63;
  const int wave = tid >> 6;
  const int wm = wave >> 1;
  const int kq = lane >> 4;

  float local = 0.f;
#pragma unroll
  for (int mi = 0; mi < 4; ++mi)
#pragma unroll
    for (int r = 0; r < 4; ++r) {
      const int grow = m0 + wm * 64 + mi * 16 + kq * 4 + r;
      const float es = lse[grow], et = lse[BT + grow];
#pragma unroll
      for (int ni = 0; ni < 4; ++ni) {
        const float ls = acc_s[mi][ni][r] - es;
        const float lt = acc_t[mi][ni][r] - et;
        const float p = __expf(ls), q = __expf(lt);
        local += p * ls + q * lt - (p + q) * __logf(p + q);
      }
    }
  local += __shfl_xor(local, 1);
  local += __shfl_xor(local, 2);
  local += __shfl_xor(local, 4);
  local += __shfl_xor(local, 8);
  local += __shfl_xor(local, 16);
  local += __shfl_xor(local, 32);
  if (lane == 0) red[wave] = local;
  __syncthreads();
  if (tid == 0) atomicAdd(out, (red[0] + red[1] + red[2] + red[3]) * (0.5f / BT));
}

extern "C" void kernel_launch(void* const* d_in, const int* in_sizes, int n_in,
                              void* d_out, int out_size, void* d_ws, size_t ws_size,
                              hipStream_t stream) {
  const float* Xs = (const float*)d_in[0];
  const float* Xt = (const float*)d_in[1];
  const float* Ws = (const float*)d_in[2];
  const float* Wt = (const float*)d_in[3];
  float* out = (float*)d_out;
  char* ws = (char*)d_ws;

  const size_t STATS_B = (size_t)2 * BT * sizeof(float);          // 32 KB
  const size_t XB8 = (size_t)BT * HD;                             // fp8 X (8 MB)
  const size_t WB8 = (size_t)VD * HD;                             // fp8 W (65.5 MB)
  const size_t XB = (size_t)BT * HD * 2;                          // bf16 X
  const size_t WB = (size_t)VD * HD * 2;                          // bf16 W
  const size_t LOGIT_B = (size_t)2 * BT * VD * 2;                 // bf16 logits (s+t)
  const size_t FP8_NEED = STATS_B + 2 * XB8 + 2 * WB8 + LOGIT_B;  // ~672 MB
  const size_t PRECAST_NEED = STATS_B + 2 * XB + 2 * WB;          // ~296 MB
  const size_t MID_NEED = STATS_B + LOGIT_B;                      // ~524 MB

  float* stats = (float*)ws;

  const dim3 blk(256);
  const dim3 g1(BT / BM, VD / BN, 2);
  const dim3 g2(BT / BM, VD / BN, 1);
  const int XN4 = BT * HD / 4;
  const int WN4 = VD * HD / 4;

  if (ws_size >= FP8_NEED) {
    // fp8 GEMM path: cast to k-interleaved e4m3 (W prescaled x64; also
    // zeroes stats + seeds out), 128^2 fp8 ring-2 pipeline with band-major
    // locality order, loss from bf16 logits (NT loads).
    unsigned char* fXs = (unsigned char*)(ws + STATS_B);
    unsigned char* fXt = fXs + XB8;
    unsigned char* fWs = fXt + XB8;
    unsigned char* fWt = fWs + WB8;
    unsigned short* logits = (unsigned short*)(ws + STATS_B + 2 * XB8 + 2 * WB8);
    cast_all_fp8i<<<dim3(2048), blk, 0, stream>>>(
        Xs, Xt, Ws, Wt,
        (uint4_t*)fXs, (uint4_t*)fXt, (uint4_t*)fWs, (uint4_t*)fWt, stats, out);
    gemm128_fp8_pass1<<<dim3((BT / 128) * (VD / 128), 2), dim3(256), 0, stream>>>(
        fXs, fXt, fWs, fWt, stats, logits);
    loss_from_blogits<<<dim3(BT), blk, 0, stream>>>(
        (const ushort8_t*)logits,
        (const ushort8_t*)(logits + (size_t)BT * VD), stats, out);
  } else if (ws_size >= MID_NEED) {
    // no precast: stage f32->bf16 on the fly, materialize bf16 logits
    unsigned short* logits = (unsigned short*)(ws + STATS_B);
    hipMemsetAsync(stats, 0, STATS_B, stream);
    gemm_pass1<true, true><<<g1, blk, 0, stream>>>(Xs, Xt, Ws, Wt, stats, logits);
    seed_out<<<dim3(1), dim3(1), 0, stream>>>(out);
    loss_from_blogits<<<dim3(BT), blk, 0, stream>>>(
        (const ushort8_t*)logits,
        (const ushort8_t*)(logits + (size_t)BT * VD), stats, out);
  } else if (ws_size >= PRECAST_NEED) {
    // precast bf16, recompute logits in pass 2
    unsigned short* bXs = (unsigned short*)(ws + STATS_B);
    unsigned short* bXt = bXs + (size_t)BT * HD;
    unsigned short* bWs = bXt + (size_t)BT * HD;
    unsigned short* bWt = bWs + (size_t)VD * HD;
    hipMemsetAsync(stats, 0, STATS_B, stream);
    cast_f32_to_bf16<<<dim3(512), blk, 0, stream>>>((const float4_t*)Xs, (short4_t*)bXs, XN4);
    cast_f32_to_bf16<<<dim3(512), blk, 0, stream>>>((const float4_t*)Xt, (short4_t*)bXt, XN4);
    cast_f32_to_bf16<<<dim3(2048), blk, 0, stream>>>((const float4_t*)Ws, (short4_t*)bWs, WN4);
    cast_f32_to_bf16<<<dim3(2048), blk, 0, stream>>>((const float4_t*)Wt, (short4_t*)bWt, WN4);
    gemm_pass1<false, false><<<g1, blk, 0, stream>>>(bXs, bXt, bWs, bWt, stats, nullptr);
    lse_fix<<<dim3(32), blk, 0, stream>>>(stats, out);
    gemm_loss<false><<<g2, blk, 0, stream>>>(bXs, bWs, bXt, bWt, stats, out);
  } else {
    // minimal-ws fallback: everything on the fly (needs only 32 KB)
    hipMemsetAsync(stats, 0, STATS_B, stream);
    gemm_pass1<true, false><<<g1, blk, 0, stream>>>(Xs, Xt, Ws, Wt, stats, nullptr);
    lse_fix<<<dim3(32), blk, 0, stream>>>(stats, out);
    gemm_loss<true><<<g2, blk, 0, stream>>>(Xs, Ws, Xt, Wt, stats, out);
  }
  (void)in_sizes; (void)n_in; (void)out_size;
}